// Round 1
// baseline (1592.507 us; speedup 1.0000x reference)
//
#include <hip/hip_runtime.h>
#include <math.h>

#define TPB 256
// Problem shape (derived at runtime from in_sizes, these are just for LDS sizing)
#define D_IN 16
#define D_OUT 32
#define NUM_K 8

// ---------------- counting-sort pipeline ----------------

__global__ void k_zero(int* __restrict__ cnt, float* __restrict__ stats, int N) {
    int i = blockIdx.x * TPB + threadIdx.x;
    if (i < N) cnt[i] = 0;
    if (blockIdx.x == 0 && threadIdx.x < 64) stats[threadIdx.x] = 0.f;
}

__global__ void k_hist(const int* __restrict__ dst, int* __restrict__ cnt, int E) {
    int e = blockIdx.x * TPB + threadIdx.x;
    if (e < E) atomicAdd(&cnt[dst[e]], 1);
}

__global__ void k_scan_a(const int* __restrict__ cnt, int* __restrict__ bsum, int N) {
    __shared__ int sd[TPB];
    int i = blockIdx.x * TPB + threadIdx.x;
    sd[threadIdx.x] = (i < N) ? cnt[i] : 0;
    __syncthreads();
    for (int s = TPB / 2; s > 0; s >>= 1) {
        if (threadIdx.x < s) sd[threadIdx.x] += sd[threadIdx.x + s];
        __syncthreads();
    }
    if (threadIdx.x == 0) bsum[blockIdx.x] = sd[0];
}

// single block, 512 threads: exclusive scan of block sums (nb <= 512)
__global__ void k_scan_b(const int* __restrict__ bsum, int* __restrict__ boff, int nb) {
    __shared__ int sd[512];
    int t = threadIdx.x;
    int own = (t < nb) ? bsum[t] : 0;
    sd[t] = own;
    __syncthreads();
    for (int s = 1; s < 512; s <<= 1) {
        int a = sd[t];
        int b = (t >= s) ? sd[t - s] : 0;
        __syncthreads();
        sd[t] = a + b;
        __syncthreads();
    }
    if (t < nb) boff[t] = sd[t] - own;   // exclusive
}

__global__ void k_scan_c(const int* __restrict__ cnt, const int* __restrict__ boff,
                         int* __restrict__ row_start, int* __restrict__ cursor,
                         int N, int E) {
    __shared__ int sd[TPB];
    int t = threadIdx.x;
    int i = blockIdx.x * TPB + t;
    int v = (i < N) ? cnt[i] : 0;
    sd[t] = v;
    __syncthreads();
    for (int s = 1; s < TPB; s <<= 1) {
        int a = sd[t];
        int b = (t >= s) ? sd[t - s] : 0;
        __syncthreads();
        sd[t] = a + b;
        __syncthreads();
    }
    int excl = sd[t] - v + boff[blockIdx.x];
    if (i < N) { row_start[i] = excl; cursor[i] = excl; }
    if (i == 0) row_start[N] = E;
}

__global__ void k_scatter(const int* __restrict__ dst, int* __restrict__ cursor,
                          int* __restrict__ sorted_eid, int E) {
    int e = blockIdx.x * TPB + threadIdx.x;
    if (e < E) {
        int pos = atomicAdd(&cursor[dst[e]], 1);
        sorted_eid[pos] = e;
    }
}

// ---------------- main aggregation kernel: one thread per node ----------------

__global__ __launch_bounds__(TPB) void k_agg(
    const float* __restrict__ x, const int* __restrict__ src,
    const float* __restrict__ attr, const float* __restrict__ W,
    const float* __restrict__ Wr, const float* __restrict__ bias,
    const int* __restrict__ row_start, const int* __restrict__ sorted_eid,
    float* __restrict__ out, float* __restrict__ stats, int N) {
    __shared__ float sW[NUM_K * D_IN * D_OUT];   // 16 KB
    __shared__ float sWr[D_IN * D_OUT];          // 2 KB
    __shared__ float sB[D_OUT];
    for (int i = threadIdx.x; i < NUM_K * D_IN * D_OUT; i += TPB) sW[i] = W[i];
    for (int i = threadIdx.x; i < D_IN * D_OUT; i += TPB) sWr[i] = Wr[i];
    if (threadIdx.x < D_OUT) sB[threadIdx.x] = bias[threadIdx.x];
    __syncthreads();

    int n = blockIdx.x * TPB + threadIdx.x;

    float g[NUM_K][D_IN];
#pragma unroll
    for (int k = 0; k < NUM_K; k++)
#pragma unroll
        for (int i = 0; i < D_IN; i++) g[k][i] = 0.f;

    int deg = 0;
    if (n < N) {
        int p0 = row_start[n], p1 = row_start[n + 1];
        deg = p1 - p0;
        for (int p = p0; p < p1; ++p) {
            int e  = sorted_eid[p];
            int sn = src[e];
            float f0 = attr[3 * e + 0], f1 = attr[3 * e + 1], f2 = attr[3 * e + 2];
            float a0 = 1.f - f0, a1 = 1.f - f1, a2 = 1.f - f2;
            const float4* xp = (const float4*)(x + (size_t)sn * D_IN);
            float4 v0 = xp[0], v1 = xp[1], v2 = xp[2], v3 = xp[3];
            float xj[D_IN] = {v0.x, v0.y, v0.z, v0.w, v1.x, v1.y, v1.z, v1.w,
                              v2.x, v2.y, v2.z, v2.w, v3.x, v3.y, v3.z, v3.w};
            // degree-1 open B-spline basis, flat index k = i0 + 2*i1 + 4*i2
            float bs[NUM_K] = {a0 * a1 * a2, f0 * a1 * a2, a0 * f1 * a2, f0 * f1 * a2,
                               a0 * a1 * f2, f0 * a1 * f2, a0 * f1 * f2, f0 * f1 * f2};
#pragma unroll
            for (int k = 0; k < NUM_K; k++) {
                float bk = bs[k];
#pragma unroll
                for (int i = 0; i < D_IN; i++) g[k][i] = fmaf(bk, xj[i], g[k][i]);
            }
        }
    }

    // o[c] = (sum_{k,i} g[k][i] * W[k,i,c]) / max(deg,1)
    float o[D_OUT];
#pragma unroll
    for (int c = 0; c < D_OUT; c++) o[c] = 0.f;
#pragma unroll
    for (int k = 0; k < NUM_K; k++)
#pragma unroll
        for (int i = 0; i < D_IN; i++) {
            float gv = g[k][i];
            const float4* wrow = (const float4*)&sW[(k * D_IN + i) * D_OUT];
#pragma unroll
            for (int c4 = 0; c4 < D_OUT / 4; c4++) {
                float4 w = wrow[c4];
                o[c4 * 4 + 0] = fmaf(gv, w.x, o[c4 * 4 + 0]);
                o[c4 * 4 + 1] = fmaf(gv, w.y, o[c4 * 4 + 1]);
                o[c4 * 4 + 2] = fmaf(gv, w.z, o[c4 * 4 + 2]);
                o[c4 * 4 + 3] = fmaf(gv, w.w, o[c4 * 4 + 3]);
            }
        }
    float inv = 1.f / (float)(deg > 0 ? deg : 1);
#pragma unroll
    for (int c = 0; c < D_OUT; c++) o[c] *= inv;

    if (n < N) {
        // + x @ W_root
#pragma unroll
        for (int i = 0; i < D_IN; i++) {
            float xv = x[(size_t)n * D_IN + i];
            const float4* wrow = (const float4*)&sWr[i * D_OUT];
#pragma unroll
            for (int c4 = 0; c4 < D_OUT / 4; c4++) {
                float4 w = wrow[c4];
                o[c4 * 4 + 0] = fmaf(xv, w.x, o[c4 * 4 + 0]);
                o[c4 * 4 + 1] = fmaf(xv, w.y, o[c4 * 4 + 1]);
                o[c4 * 4 + 2] = fmaf(xv, w.z, o[c4 * 4 + 2]);
                o[c4 * 4 + 3] = fmaf(xv, w.w, o[c4 * 4 + 3]);
            }
        }
        // + bias, ELU
#pragma unroll
        for (int c = 0; c < D_OUT; c++) {
            float v = o[c] + sB[c];
            o[c] = v > 0.f ? v : (expf(v) - 1.f);
        }
        // store pre-BN output
        float4* op = (float4*)(out + (size_t)n * D_OUT);
#pragma unroll
        for (int c4 = 0; c4 < D_OUT / 4; c4++)
            op[c4] = make_float4(o[c4 * 4 + 0], o[c4 * 4 + 1], o[c4 * 4 + 2], o[c4 * 4 + 3]);
    } else {
#pragma unroll
        for (int c = 0; c < D_OUT; c++) o[c] = 0.f;   // zero contribution to stats
    }

    // per-channel batch stats: wave-wide shuffle reduce, then 64 atomics/wave
#pragma unroll
    for (int c = 0; c < D_OUT; c++) {
        float s = o[c], q = o[c] * o[c];
#pragma unroll
        for (int m = 1; m < 64; m <<= 1) {
            s += __shfl_xor(s, m);
            q += __shfl_xor(q, m);
        }
        if ((threadIdx.x & 63) == 0) {
            atomicAdd(&stats[c], s);
            atomicAdd(&stats[D_OUT + c], q);
        }
    }
}

// ---------------- batchnorm ----------------

__global__ void k_bnfin(float* __restrict__ stats, const float* __restrict__ gamma,
                        const float* __restrict__ beta, int N) {
    int c = threadIdx.x;
    if (c < D_OUT) {
        float mean = stats[c] / (float)N;
        float var  = stats[D_OUT + c] / (float)N - mean * mean;
        float sc   = gamma[c] * rsqrtf(var + 1e-5f);
        stats[64 + c] = sc;
        stats[96 + c] = beta[c] - mean * sc;
    }
}

__global__ void k_bnapply(float* __restrict__ out, const float* __restrict__ stats, int total4) {
    int i = blockIdx.x * TPB + threadIdx.x;
    if (i < total4) {
        float4 v = ((float4*)out)[i];
        int c0 = (i * 4) & (D_OUT - 1);
        v.x = v.x * stats[64 + c0 + 0] + stats[96 + c0 + 0];
        v.y = v.y * stats[64 + c0 + 1] + stats[96 + c0 + 1];
        v.z = v.z * stats[64 + c0 + 2] + stats[96 + c0 + 2];
        v.w = v.w * stats[64 + c0 + 3] + stats[96 + c0 + 3];
        ((float4*)out)[i] = v;
    }
}

// ---------------- launcher ----------------

extern "C" void kernel_launch(void* const* d_in, const int* in_sizes, int n_in,
                              void* d_out, int out_size, void* d_ws, size_t ws_size,
                              hipStream_t stream) {
    const float* x     = (const float*)d_in[0];
    const int* eidx    = (const int*)d_in[1];
    const float* attr  = (const float*)d_in[2];
    const float* W     = (const float*)d_in[3];
    const float* Wr    = (const float*)d_in[4];
    const float* bias  = (const float*)d_in[5];
    const float* gamma = (const float*)d_in[6];
    const float* beta  = (const float*)d_in[7];
    float* out = (float*)d_out;

    const int N = in_sizes[0] / D_IN;
    const int E = in_sizes[1] / 2;
    const int* src = eidx;
    const int* dst = eidx + E;

    const int nb = (N + TPB - 1) / TPB;      // 391 for N=100000 (<=512 required by scan_b)
    const int gE = (E + TPB - 1) / TPB;

    // workspace layout (all 4-byte elements)
    int* cnt        = (int*)d_ws;            // N
    int* row_start  = cnt + N;               // N+1
    int* cursor     = row_start + N + 1;     // N
    int* bsum       = cursor + N;            // nb
    int* boff       = bsum + nb;             // nb
    int* sorted_eid = boff + nb;             // E
    float* stats    = (float*)(sorted_eid + E); // 128: sum[32] sumsq[32] scale[32] shift[32]

    k_zero<<<nb, TPB, 0, stream>>>(cnt, stats, N);
    k_hist<<<gE, TPB, 0, stream>>>(dst, cnt, E);
    k_scan_a<<<nb, TPB, 0, stream>>>(cnt, bsum, N);
    k_scan_b<<<1, 512, 0, stream>>>(bsum, boff, nb);
    k_scan_c<<<nb, TPB, 0, stream>>>(cnt, boff, row_start, cursor, N, E);
    k_scatter<<<gE, TPB, 0, stream>>>(dst, cursor, sorted_eid, E);
    k_agg<<<nb, TPB, 0, stream>>>(x, src, attr, W, Wr, bias, row_start, sorted_eid,
                                  out, stats, N);
    k_bnfin<<<1, 64, 0, stream>>>(stats, gamma, beta, N);
    int total4 = N * D_OUT / 4;
    k_bnapply<<<(total4 + TPB - 1) / TPB, TPB, 0, stream>>>(out, stats, total4);
}

// Round 2
// 1472.103 us; speedup vs baseline: 1.0818x; 1.0818x over previous
//
#include <hip/hip_runtime.h>
#include <math.h>

#define TPB 256
#define D_IN 16
#define D_OUT 32
#define NUM_K 8

// ---------------- counting-sort pipeline ----------------

__global__ void k_zero(int* __restrict__ cnt, float* __restrict__ stats, int N) {
    int i = blockIdx.x * TPB + threadIdx.x;
    if (i < N) cnt[i] = 0;
    if (blockIdx.x == 0 && threadIdx.x < 64) stats[threadIdx.x] = 0.f;
}

__global__ void k_hist(const int* __restrict__ dst, int* __restrict__ cnt, int E) {
    int e = blockIdx.x * TPB + threadIdx.x;
    if (e < E) atomicAdd(&cnt[dst[e]], 1);
}

__global__ void k_scan_a(const int* __restrict__ cnt, int* __restrict__ bsum, int N) {
    __shared__ int sd[TPB];
    int i = blockIdx.x * TPB + threadIdx.x;
    sd[threadIdx.x] = (i < N) ? cnt[i] : 0;
    __syncthreads();
    for (int s = TPB / 2; s > 0; s >>= 1) {
        if (threadIdx.x < s) sd[threadIdx.x] += sd[threadIdx.x + s];
        __syncthreads();
    }
    if (threadIdx.x == 0) bsum[blockIdx.x] = sd[0];
}

// single block, 512 threads: exclusive scan of block sums (nb <= 512)
__global__ void k_scan_b(const int* __restrict__ bsum, int* __restrict__ boff, int nb) {
    __shared__ int sd[512];
    int t = threadIdx.x;
    int own = (t < nb) ? bsum[t] : 0;
    sd[t] = own;
    __syncthreads();
    for (int s = 1; s < 512; s <<= 1) {
        int a = sd[t];
        int b = (t >= s) ? sd[t - s] : 0;
        __syncthreads();
        sd[t] = a + b;
        __syncthreads();
    }
    if (t < nb) boff[t] = sd[t] - own;   // exclusive
}

// cursor[i] = exclusive prefix (row start); after k_scatter, cursor[i] == row end
__global__ void k_scan_c(const int* __restrict__ cnt, const int* __restrict__ boff,
                         int* __restrict__ cursor, int N) {
    __shared__ int sd[TPB];
    int t = threadIdx.x;
    int i = blockIdx.x * TPB + t;
    int v = (i < N) ? cnt[i] : 0;
    sd[t] = v;
    __syncthreads();
    for (int s = 1; s < TPB; s <<= 1) {
        int a = sd[t];
        int b = (t >= s) ? sd[t - s] : 0;
        __syncthreads();
        sd[t] = a + b;
        __syncthreads();
    }
    if (i < N) cursor[i] = sd[t] - v + boff[blockIdx.x];
}

// scatter packed edge records to sorted-by-dst positions
// rec = {src, q0 | q1<<10 | q2<<20} with q = floor(attr * 1024)
__global__ void k_scatter(const int* __restrict__ src, const int* __restrict__ dst,
                          const float* __restrict__ attr, int* __restrict__ cursor,
                          uint2* __restrict__ rec, int E) {
    int e = blockIdx.x * TPB + threadIdx.x;
    if (e < E) {
        float f0 = attr[3 * e + 0], f1 = attr[3 * e + 1], f2 = attr[3 * e + 2];
        int q0 = min((int)(f0 * 1024.f), 1023);
        int q1 = min((int)(f1 * 1024.f), 1023);
        int q2 = min((int)(f2 * 1024.f), 1023);
        unsigned pk = (unsigned)q0 | ((unsigned)q1 << 10) | ((unsigned)q2 << 20);
        int pos = atomicAdd(&cursor[dst[e]], 1);
        rec[pos] = make_uint2((unsigned)src[e], pk);
    }
}

// ---------------- main aggregation kernel: one QUAD (4 threads) per node ----------------
// lane h of a quad owns input dims 4h..4h+3 -> g[8][4] accumulator (32 VGPRs)

__global__ __launch_bounds__(TPB) void k_agg(
    const float* __restrict__ x, const float* __restrict__ W,
    const float* __restrict__ Wr, const float* __restrict__ bias,
    const int* __restrict__ cursor, const uint2* __restrict__ rec,
    float* __restrict__ out, float* __restrict__ stats, int N) {
    // per-h padded layout: h-block stride 1028 floats -> quad lanes hit banks {4h..4h+3}
    __shared__ __align__(16) float sW[4 * 1028];   // W[k,i,c] at [i/4]*1028 + (k*4+i%4)*32 + c
    __shared__ __align__(16) float sWr[4 * 132];   // Wr[i,c]  at [i/4]*132  + (i%4)*32 + c
    __shared__ float sB[D_OUT];
    for (int idx = threadIdx.x; idx < NUM_K * D_IN * D_OUT; idx += TPB) {
        int k = idx >> 9, rem = idx & 511, i = rem >> 5, c = rem & 31;
        sW[(i >> 2) * 1028 + ((k << 2) + (i & 3)) * 32 + c] = W[idx];
    }
    for (int idx = threadIdx.x; idx < D_IN * D_OUT; idx += TPB) {
        int i = idx >> 5, c = idx & 31;
        sWr[(i >> 2) * 132 + (i & 3) * 32 + c] = Wr[idx];
    }
    if (threadIdx.x < D_OUT) sB[threadIdx.x] = bias[threadIdx.x];
    __syncthreads();

    int t = blockIdx.x * TPB + threadIdx.x;
    int n = t >> 2;
    int h = t & 3;

    float g[NUM_K][4];
#pragma unroll
    for (int k = 0; k < NUM_K; k++)
#pragma unroll
        for (int j = 0; j < 4; j++) g[k][j] = 0.f;

    int deg = 0;
    if (n < N) {
        int p0 = (n == 0) ? 0 : cursor[n - 1];   // quad-uniform broadcast loads
        int p1 = cursor[n];
        deg = p1 - p0;
        uint2 r = (p0 < p1) ? rec[p0] : make_uint2(0u, 0u);
        for (int p = p0; p < p1; ++p) {
            uint2 rn = (p + 1 < p1) ? rec[p + 1] : r;    // prefetch next record
            int sn = (int)r.x;
            float f0 = ((float)(r.y & 1023u) + 0.5f) * (1.f / 1024.f);
            float f1 = ((float)((r.y >> 10) & 1023u) + 0.5f) * (1.f / 1024.f);
            float f2 = ((float)((r.y >> 20) & 1023u) + 0.5f) * (1.f / 1024.f);
            float a0 = 1.f - f0, a1 = 1.f - f1, a2 = 1.f - f2;
            float4 xq = ((const float4*)x)[(size_t)sn * 4 + h];  // quad-coalesced 64B row
            float bs[NUM_K] = {a0 * a1 * a2, f0 * a1 * a2, a0 * f1 * a2, f0 * f1 * a2,
                               a0 * a1 * f2, f0 * a1 * f2, a0 * f1 * f2, f0 * f1 * f2};
#pragma unroll
            for (int k = 0; k < NUM_K; k++) {
                g[k][0] = fmaf(bs[k], xq.x, g[k][0]);
                g[k][1] = fmaf(bs[k], xq.y, g[k][1]);
                g[k][2] = fmaf(bs[k], xq.z, g[k][2]);
                g[k][3] = fmaf(bs[k], xq.w, g[k][3]);
            }
            r = rn;
        }
    }

    // partial contraction over this lane's 4 input dims: o[c] = sum_{k,j} g*W
    float o[D_OUT];
#pragma unroll
    for (int c = 0; c < D_OUT; c++) o[c] = 0.f;
    const float4* sW4 = (const float4*)&sW[h * 1028];
#pragma unroll
    for (int k = 0; k < NUM_K; k++)
#pragma unroll
        for (int j = 0; j < 4; j++) {
            float gv = g[k][j];
            int base4 = ((k << 2) + j) * 8;
#pragma unroll
            for (int c4 = 0; c4 < 8; c4++) {
                float4 w = sW4[base4 + c4];
                o[c4 * 4 + 0] = fmaf(gv, w.x, o[c4 * 4 + 0]);
                o[c4 * 4 + 1] = fmaf(gv, w.y, o[c4 * 4 + 1]);
                o[c4 * 4 + 2] = fmaf(gv, w.z, o[c4 * 4 + 2]);
                o[c4 * 4 + 3] = fmaf(gv, w.w, o[c4 * 4 + 3]);
            }
        }
    float inv = 1.f / (float)(deg > 0 ? deg : 1);
#pragma unroll
    for (int c = 0; c < D_OUT; c++) o[c] *= inv;

    // + root-weight partial (this lane's 4 dims), before the quad reduce
    if (n < N) {
        float4 xr = ((const float4*)x)[(size_t)n * 4 + h];
        const float4* sWr4 = (const float4*)&sWr[h * 132];
        float xv[4] = {xr.x, xr.y, xr.z, xr.w};
#pragma unroll
        for (int j = 0; j < 4; j++) {
#pragma unroll
            for (int c4 = 0; c4 < 8; c4++) {
                float4 w = sWr4[j * 8 + c4];
                o[c4 * 4 + 0] = fmaf(xv[j], w.x, o[c4 * 4 + 0]);
                o[c4 * 4 + 1] = fmaf(xv[j], w.y, o[c4 * 4 + 1]);
                o[c4 * 4 + 2] = fmaf(xv[j], w.z, o[c4 * 4 + 2]);
                o[c4 * 4 + 3] = fmaf(xv[j], w.w, o[c4 * 4 + 3]);
            }
        }
    }

    // quad reduce-scatter via predicated selects (no runtime register indexing):
    // stage A (xor 2): h&2 picks half 16..31; stage B (xor 1): h&1 picks odd 8-block.
    // lane h ends owning channels 8h..8h+7.
    bool hi2 = (h & 2) != 0;
    float p1v[16];
#pragma unroll
    for (int c = 0; c < 16; c++) {
        float keep = hi2 ? o[c + 16] : o[c];
        float send = hi2 ? o[c] : o[c + 16];
        p1v[c] = keep + __shfl_xor(send, 2);
    }
    bool hi1 = (h & 1) != 0;
    float p2v[8];
#pragma unroll
    for (int c = 0; c < 8; c++) {
        float keep = hi1 ? p1v[c + 8] : p1v[c];
        float send = hi1 ? p1v[c] : p1v[c + 8];
        p2v[c] = keep + __shfl_xor(send, 1);
    }

    // + bias, ELU on owned channels
    float ev[8];
    const float4* sB4 = (const float4*)sB;
    float4 b0 = sB4[h * 2 + 0], b1 = sB4[h * 2 + 1];
    float bv[8] = {b0.x, b0.y, b0.z, b0.w, b1.x, b1.y, b1.z, b1.w};
#pragma unroll
    for (int c = 0; c < 8; c++) {
        float v = p2v[c] + bv[c];
        ev[c] = v > 0.f ? v : (expf(v) - 1.f);
    }

    if (n < N) {
        float4* op = (float4*)(out + (size_t)n * D_OUT + h * 8);
        op[0] = make_float4(ev[0], ev[1], ev[2], ev[3]);
        op[1] = make_float4(ev[4], ev[5], ev[6], ev[7]);
    }

    // batch stats: channels 8h+c; reduce across the 16 quads of the wave
#pragma unroll
    for (int c = 0; c < 8; c++) {
        float s = (n < N) ? ev[c] : 0.f;
        float q = s * s;
#pragma unroll
        for (int m = 4; m < 64; m <<= 1) {
            s += __shfl_xor(s, m);
            q += __shfl_xor(q, m);
        }
        if ((threadIdx.x & 63) < 4) {
            atomicAdd(&stats[h * 8 + c], s);
            atomicAdd(&stats[D_OUT + h * 8 + c], q);
        }
    }
}

// ---------------- batchnorm ----------------

__global__ void k_bnfin(float* __restrict__ stats, const float* __restrict__ gamma,
                        const float* __restrict__ beta, int N) {
    int c = threadIdx.x;
    if (c < D_OUT) {
        float mean = stats[c] / (float)N;
        float var  = stats[D_OUT + c] / (float)N - mean * mean;
        float sc   = gamma[c] * rsqrtf(var + 1e-5f);
        stats[64 + c] = sc;
        stats[96 + c] = beta[c] - mean * sc;
    }
}

__global__ void k_bnapply(float* __restrict__ out, const float* __restrict__ stats, int total4) {
    int i = blockIdx.x * TPB + threadIdx.x;
    if (i < total4) {
        float4 v = ((float4*)out)[i];
        int c0 = (i * 4) & (D_OUT - 1);
        v.x = v.x * stats[64 + c0 + 0] + stats[96 + c0 + 0];
        v.y = v.y * stats[64 + c0 + 1] + stats[96 + c0 + 1];
        v.z = v.z * stats[64 + c0 + 2] + stats[96 + c0 + 2];
        v.w = v.w * stats[64 + c0 + 3] + stats[96 + c0 + 3];
        ((float4*)out)[i] = v;
    }
}

// ---------------- launcher ----------------

extern "C" void kernel_launch(void* const* d_in, const int* in_sizes, int n_in,
                              void* d_out, int out_size, void* d_ws, size_t ws_size,
                              hipStream_t stream) {
    const float* x     = (const float*)d_in[0];
    const int* eidx    = (const int*)d_in[1];
    const float* attr  = (const float*)d_in[2];
    const float* W     = (const float*)d_in[3];
    const float* Wr    = (const float*)d_in[4];
    const float* bias  = (const float*)d_in[5];
    const float* gamma = (const float*)d_in[6];
    const float* beta  = (const float*)d_in[7];
    float* out = (float*)d_out;

    const int N = in_sizes[0] / D_IN;
    const int E = in_sizes[1] / 2;
    const int* src = eidx;
    const int* dst = eidx + E;

    const int nb = (N + TPB - 1) / TPB;      // 391 for N=100000 (<=512 required by scan_b)
    const int gE = (E + TPB - 1) / TPB;

    // workspace layout
    uint2* rec   = (uint2*)d_ws;                 // E   (8B each)
    int* cnt     = (int*)(rec + E);              // N
    int* cursor  = cnt + N;                      // N
    int* bsum    = cursor + N;                   // nb
    int* boff    = bsum + nb;                    // nb
    float* stats = (float*)(boff + nb);          // 128: sum[32] sumsq[32] scale[32] shift[32]

    k_zero<<<nb, TPB, 0, stream>>>(cnt, stats, N);
    k_hist<<<gE, TPB, 0, stream>>>(dst, cnt, E);
    k_scan_a<<<nb, TPB, 0, stream>>>(cnt, bsum, N);
    k_scan_b<<<1, 512, 0, stream>>>(bsum, boff, nb);
    k_scan_c<<<nb, TPB, 0, stream>>>(cnt, boff, cursor, N);
    k_scatter<<<gE, TPB, 0, stream>>>(src, dst, attr, cursor, rec, E);

    const int gA = (4 * N + TPB - 1) / TPB;      // one quad per node
    k_agg<<<gA, TPB, 0, stream>>>(x, W, Wr, bias, cursor, rec, out, stats, N);

    k_bnfin<<<1, 64, 0, stream>>>(stats, gamma, beta, N);
    int total4 = N * D_OUT / 4;
    k_bnapply<<<(total4 + TPB - 1) / TPB, TPB, 0, stream>>>(out, stats, total4);
}

// Round 3
// 475.059 us; speedup vs baseline: 3.3522x; 3.0988x over previous
//
#include <hip/hip_runtime.h>
#include <math.h>

#define TPB 256
#define D_IN 16
#define D_OUT 32
#define NUM_K 8
#define WPAD 516   // 512 + 4 floats: kernel-h stride in LDS, banks 4h..4h+3

// ---------------- counting-sort pipeline ----------------

__global__ void k_zero(int* __restrict__ cnt, int N) {
    int i = blockIdx.x * TPB + threadIdx.x;
    if (i < N) cnt[i] = 0;
}

__global__ void k_hist(const int* __restrict__ dst, int* __restrict__ cnt, int E) {
    int e = blockIdx.x * TPB + threadIdx.x;
    if (e < E) atomicAdd(&cnt[dst[e]], 1);
}

__global__ void k_scan_a(const int* __restrict__ cnt, int* __restrict__ bsum, int N) {
    __shared__ int sd[TPB];
    int i = blockIdx.x * TPB + threadIdx.x;
    sd[threadIdx.x] = (i < N) ? cnt[i] : 0;
    __syncthreads();
    for (int s = TPB / 2; s > 0; s >>= 1) {
        if (threadIdx.x < s) sd[threadIdx.x] += sd[threadIdx.x + s];
        __syncthreads();
    }
    if (threadIdx.x == 0) bsum[blockIdx.x] = sd[0];
}

// single block, 512 threads: exclusive scan of block sums (nb <= 512)
__global__ void k_scan_b(const int* __restrict__ bsum, int* __restrict__ boff, int nb) {
    __shared__ int sd[512];
    int t = threadIdx.x;
    int own = (t < nb) ? bsum[t] : 0;
    sd[t] = own;
    __syncthreads();
    for (int s = 1; s < 512; s <<= 1) {
        int a = sd[t];
        int b = (t >= s) ? sd[t - s] : 0;
        __syncthreads();
        sd[t] = a + b;
        __syncthreads();
    }
    if (t < nb) boff[t] = sd[t] - own;   // exclusive
}

// cursor[i] = exclusive prefix (row start); after k_scatter, cursor[i] == row end
__global__ void k_scan_c(const int* __restrict__ cnt, const int* __restrict__ boff,
                         int* __restrict__ cursor, int N) {
    __shared__ int sd[TPB];
    int t = threadIdx.x;
    int i = blockIdx.x * TPB + t;
    int v = (i < N) ? cnt[i] : 0;
    sd[t] = v;
    __syncthreads();
    for (int s = 1; s < TPB; s <<= 1) {
        int a = sd[t];
        int b = (t >= s) ? sd[t - s] : 0;
        __syncthreads();
        sd[t] = a + b;
        __syncthreads();
    }
    if (i < N) cursor[i] = sd[t] - v + boff[blockIdx.x];
}

// scatter packed edge records to sorted-by-dst positions
// rec = {src, q0 | q1<<10 | q2<<20} with q = floor(attr * 1024)
__global__ void k_scatter(const int* __restrict__ src, const int* __restrict__ dst,
                          const float* __restrict__ attr, int* __restrict__ cursor,
                          uint2* __restrict__ rec, int E) {
    int e = blockIdx.x * TPB + threadIdx.x;
    if (e < E) {
        float f0 = attr[3 * e + 0], f1 = attr[3 * e + 1], f2 = attr[3 * e + 2];
        int q0 = min((int)(f0 * 1024.f), 1023);
        int q1 = min((int)(f1 * 1024.f), 1023);
        int q2 = min((int)(f2 * 1024.f), 1023);
        unsigned pk = (unsigned)q0 | ((unsigned)q1 << 10) | ((unsigned)q2 << 20);
        int pos = atomicAdd(&cursor[dst[e]], 1);
        rec[pos] = make_uint2((unsigned)src[e], pk);
    }
}

// ---------------- main aggregation: 16 lanes per node ----------------
// sub = lane-in-node (0..15), grp = sub>>3 (edge parity), h = sub&7 (spline kernel).
// Lane accumulates g[16 input dims] for its kernel h over its edge subset; all
// accumulators are NAMED float4s (no arrays -> no scratch). No global atomics.

__global__ __launch_bounds__(TPB, 4) void k_agg(
    const float* __restrict__ x, const float* __restrict__ W,
    const float* __restrict__ Wr, const float* __restrict__ bias,
    const int* __restrict__ cursor, const uint2* __restrict__ rec,
    float* __restrict__ out, float* __restrict__ partials, int N) {

    __shared__ __align__(16) float sW[NUM_K * WPAD];   // ~16.5 KB
    __shared__ __align__(16) float sWr[D_IN * D_OUT];  // 2 KB
    __shared__ float sB[D_OUT];
    __shared__ float4 sStats[4][16];

    for (int idx = threadIdx.x; idx < NUM_K * D_IN * D_OUT; idx += TPB) {
        int k = idx >> 9, rem = idx & 511, i = rem >> 5, c = rem & 31;
        sW[k * WPAD + i * 32 + c] = W[idx];
    }
    for (int idx = threadIdx.x; idx < D_IN * D_OUT; idx += TPB) sWr[idx] = Wr[idx];
    if (threadIdx.x < D_OUT) sB[threadIdx.x] = bias[threadIdx.x];
    __syncthreads();

    int t   = blockIdx.x * TPB + threadIdx.x;
    int n   = t >> 4;
    int sub = t & 15;
    int grp = sub >> 3;
    int h   = sub & 7;
    bool valid = n < N;

    float4 g0 = {0,0,0,0}, g1 = {0,0,0,0}, g2 = {0,0,0,0}, g3 = {0,0,0,0};
    int deg = 0;
    if (valid) {
        int p0 = (n == 0) ? 0 : cursor[n - 1];   // cursor[n] == row end after scatter
        int p1 = cursor[n];
        deg = p1 - p0;
        int p = p0 + grp;
        if (p < p1) {
            int last = p1 - 1;
            // software pipeline: r=current rec, rn=next rec, xq=current x row
            uint2 r  = rec[p];
            uint2 rn = rec[min(p + 2, last)];
            const float4* xr = (const float4*)x + (size_t)r.x * 4;
            float4 xq0 = xr[0], xq1 = xr[1], xq2 = xr[2], xq3 = xr[3];
            for (; p < p1; p += 2) {
                uint2 rnn = rec[min(p + 4, last)];
                const float4* xnr = (const float4*)x + (size_t)rn.x * 4;
                float4 xn0 = xnr[0], xn1 = xnr[1], xn2 = xnr[2], xn3 = xnr[3];
                float f0 = ((float)(r.y & 1023u) + 0.5f) * (1.f / 1024.f);
                float f1 = ((float)((r.y >> 10) & 1023u) + 0.5f) * (1.f / 1024.f);
                float f2 = ((float)((r.y >> 20) & 1023u) + 0.5f) * (1.f / 1024.f);
                float b0 = (h & 1) ? f0 : 1.f - f0;
                float b1 = (h & 2) ? f1 : 1.f - f1;
                float b2 = (h & 4) ? f2 : 1.f - f2;
                float bs = b0 * b1 * b2;
                g0.x = fmaf(bs, xq0.x, g0.x); g0.y = fmaf(bs, xq0.y, g0.y);
                g0.z = fmaf(bs, xq0.z, g0.z); g0.w = fmaf(bs, xq0.w, g0.w);
                g1.x = fmaf(bs, xq1.x, g1.x); g1.y = fmaf(bs, xq1.y, g1.y);
                g1.z = fmaf(bs, xq1.z, g1.z); g1.w = fmaf(bs, xq1.w, g1.w);
                g2.x = fmaf(bs, xq2.x, g2.x); g2.y = fmaf(bs, xq2.y, g2.y);
                g2.z = fmaf(bs, xq2.z, g2.z); g2.w = fmaf(bs, xq2.w, g2.w);
                g3.x = fmaf(bs, xq3.x, g3.x); g3.y = fmaf(bs, xq3.y, g3.y);
                g3.z = fmaf(bs, xq3.z, g3.z); g3.w = fmaf(bs, xq3.w, g3.w);
                r = rn; rn = rnn;
                xq0 = xn0; xq1 = xn1; xq2 = xn2; xq3 = xn3;
            }
        }
    }

    // combine the two edge-groups (lanes sub and sub^8 share kernel h)
    g0.x += __shfl_xor(g0.x, 8); g0.y += __shfl_xor(g0.y, 8);
    g0.z += __shfl_xor(g0.z, 8); g0.w += __shfl_xor(g0.w, 8);
    g1.x += __shfl_xor(g1.x, 8); g1.y += __shfl_xor(g1.y, 8);
    g1.z += __shfl_xor(g1.z, 8); g1.w += __shfl_xor(g1.w, 8);
    g2.x += __shfl_xor(g2.x, 8); g2.y += __shfl_xor(g2.y, 8);
    g2.z += __shfl_xor(g2.z, 8); g2.w += __shfl_xor(g2.w, 8);
    g3.x += __shfl_xor(g3.x, 8); g3.y += __shfl_xor(g3.y, 8);
    g3.z += __shfl_xor(g3.z, 8); g3.w += __shfl_xor(g3.w, 8);

    // contraction: this lane computes channels [16*grp, 16*grp+16) for kernel h
    float4 o0 = {0,0,0,0}, o1 = {0,0,0,0}, o2 = {0,0,0,0}, o3 = {0,0,0,0};
    const float* wbase = sW + h * WPAD + grp * 16;
#define CONTRACT1(gv, i) { \
        const float4* wr_ = (const float4*)(wbase + (i) * 32); \
        float4 w0 = wr_[0], w1 = wr_[1], w2 = wr_[2], w3 = wr_[3]; \
        o0.x = fmaf(gv, w0.x, o0.x); o0.y = fmaf(gv, w0.y, o0.y); \
        o0.z = fmaf(gv, w0.z, o0.z); o0.w = fmaf(gv, w0.w, o0.w); \
        o1.x = fmaf(gv, w1.x, o1.x); o1.y = fmaf(gv, w1.y, o1.y); \
        o1.z = fmaf(gv, w1.z, o1.z); o1.w = fmaf(gv, w1.w, o1.w); \
        o2.x = fmaf(gv, w2.x, o2.x); o2.y = fmaf(gv, w2.y, o2.y); \
        o2.z = fmaf(gv, w2.z, o2.z); o2.w = fmaf(gv, w2.w, o2.w); \
        o3.x = fmaf(gv, w3.x, o3.x); o3.y = fmaf(gv, w3.y, o3.y); \
        o3.z = fmaf(gv, w3.z, o3.z); o3.w = fmaf(gv, w3.w, o3.w); }
    CONTRACT1(g0.x,  0) CONTRACT1(g0.y,  1) CONTRACT1(g0.z,  2) CONTRACT1(g0.w,  3)
    CONTRACT1(g1.x,  4) CONTRACT1(g1.y,  5) CONTRACT1(g1.z,  6) CONTRACT1(g1.w,  7)
    CONTRACT1(g2.x,  8) CONTRACT1(g2.y,  9) CONTRACT1(g2.z, 10) CONTRACT1(g2.w, 11)
    CONTRACT1(g3.x, 12) CONTRACT1(g3.y, 13) CONTRACT1(g3.z, 14) CONTRACT1(g3.w, 15)
#undef CONTRACT1

    // scatter-mean divide
    float inv = 1.f / (float)(deg > 0 ? deg : 1);
    o0.x *= inv; o0.y *= inv; o0.z *= inv; o0.w *= inv;
    o1.x *= inv; o1.y *= inv; o1.z *= inv; o1.w *= inv;
    o2.x *= inv; o2.y *= inv; o2.z *= inv; o2.w *= inv;
    o3.x *= inv; o3.y *= inv; o3.z *= inv; o3.w *= inv;

    // reduce-scatter across the 8 h-lanes: 16 -> 8 -> 4 -> 2 channels
    bool hi4 = (h & 4) != 0;
    float4 k0, k1, s0, s1;
    k0 = hi4 ? o2 : o0; k1 = hi4 ? o3 : o1;
    s0 = hi4 ? o0 : o2; s1 = hi4 ? o1 : o3;
    k0.x += __shfl_xor(s0.x, 4); k0.y += __shfl_xor(s0.y, 4);
    k0.z += __shfl_xor(s0.z, 4); k0.w += __shfl_xor(s0.w, 4);
    k1.x += __shfl_xor(s1.x, 4); k1.y += __shfl_xor(s1.y, 4);
    k1.z += __shfl_xor(s1.z, 4); k1.w += __shfl_xor(s1.w, 4);

    bool hi2 = (h & 2) != 0;
    float4 m0 = hi2 ? k1 : k0;
    float4 sm = hi2 ? k0 : k1;
    m0.x += __shfl_xor(sm.x, 2); m0.y += __shfl_xor(sm.y, 2);
    m0.z += __shfl_xor(sm.z, 2); m0.w += __shfl_xor(sm.w, 2);

    bool hi1 = (h & 1) != 0;
    float e0 = hi1 ? m0.z : m0.x;
    float e1 = hi1 ? m0.w : m0.y;
    float sa = hi1 ? m0.x : m0.z;
    float sb = hi1 ? m0.y : m0.w;
    e0 += __shfl_xor(sa, 1);
    e1 += __shfl_xor(sb, 1);
    // lane now owns channels c0 = 2*sub, c0+1

    // + root weight for owned channels
    int c0 = 2 * sub;
    if (valid) {
        const float4* xr = (const float4*)x + (size_t)n * 4;
        float4 r0 = xr[0], r1 = xr[1], r2 = xr[2], r3 = xr[3];
#define ROOT1(xv, i) { \
            float2 w = *(const float2*)(sWr + (i) * 32 + c0); \
            e0 = fmaf(xv, w.x, e0); e1 = fmaf(xv, w.y, e1); }
        ROOT1(r0.x,  0) ROOT1(r0.y,  1) ROOT1(r0.z,  2) ROOT1(r0.w,  3)
        ROOT1(r1.x,  4) ROOT1(r1.y,  5) ROOT1(r1.z,  6) ROOT1(r1.w,  7)
        ROOT1(r2.x,  8) ROOT1(r2.y,  9) ROOT1(r2.z, 10) ROOT1(r2.w, 11)
        ROOT1(r3.x, 12) ROOT1(r3.y, 13) ROOT1(r3.z, 14) ROOT1(r3.w, 15)
#undef ROOT1
    }

    // + bias, ELU
    float2 bb = *(const float2*)(sB + c0);
    e0 += bb.x; e1 += bb.y;
    e0 = e0 > 0.f ? e0 : (expf(e0) - 1.f);
    e1 = e1 > 0.f ? e1 : (expf(e1) - 1.f);

    if (valid) *(float2*)(out + (size_t)n * D_OUT + c0) = make_float2(e0, e1);

    // block-level batch stats (NO global atomics): wave reduce then LDS
    float ss0 = valid ? e0 : 0.f, ss1 = valid ? e1 : 0.f;
    float q0 = ss0 * ss0, q1 = ss1 * ss1;
    ss0 += __shfl_xor(ss0, 16); ss1 += __shfl_xor(ss1, 16);
    q0  += __shfl_xor(q0, 16);  q1  += __shfl_xor(q1, 16);
    ss0 += __shfl_xor(ss0, 32); ss1 += __shfl_xor(ss1, 32);
    q0  += __shfl_xor(q0, 32);  q1  += __shfl_xor(q1, 32);
    if ((threadIdx.x & 63) < 16)
        sStats[threadIdx.x >> 6][sub] = make_float4(ss0, ss1, q0, q1);
    __syncthreads();
    if (threadIdx.x < 64) {
        const float* sf = (const float*)sStats;
        float v = sf[threadIdx.x] + sf[64 + threadIdx.x] +
                  sf[128 + threadIdx.x] + sf[192 + threadIdx.x];
        int ssub = threadIdx.x >> 2, comp = threadIdx.x & 3;
        int col = 2 * ssub + (comp & 1) + 32 * (comp >> 1);  // 0..31 sum, 32..63 sumsq
        partials[(size_t)blockIdx.x * 64 + col] = v;
    }
}

// ---------------- stats reduction + batchnorm ----------------

__global__ void k_red1(const float* __restrict__ partials, float* __restrict__ partials2,
                       int nrows) {
    __shared__ float sd[4][64];
    int col = threadIdx.x & 63, j = threadIdx.x >> 6;
    float v = 0.f;
    for (int k = 0; k < 16; k++) {
        int r = blockIdx.x * 64 + j * 16 + k;
        if (r < nrows) v += partials[(size_t)r * 64 + col];
    }
    sd[j][col] = v;
    __syncthreads();
    if (threadIdx.x < 64)
        partials2[(size_t)blockIdx.x * 64 + threadIdx.x] =
            sd[0][threadIdx.x] + sd[1][threadIdx.x] + sd[2][threadIdx.x] + sd[3][threadIdx.x];
}

__global__ void k_bnfin(const float* __restrict__ partials2, const float* __restrict__ gamma,
                        const float* __restrict__ beta, float* __restrict__ stats,
                        int nrows2, int N) {
    __shared__ float sd[2][64];
    int col = threadIdx.x & 63, j = threadIdx.x >> 6;   // 128 threads
    float v = 0.f;
    for (int r = j; r < nrows2; r += 2) v += partials2[(size_t)r * 64 + col];
    sd[j][col] = v;
    __syncthreads();
    if (threadIdx.x < 32) {
        int c = threadIdx.x;
        float S = sd[0][c] + sd[1][c];
        float Q = sd[0][32 + c] + sd[1][32 + c];
        float mean = S / (float)N;
        float var  = Q / (float)N - mean * mean;
        float sc   = gamma[c] * rsqrtf(var + 1e-5f);
        stats[c]      = sc;                    // scale
        stats[32 + c] = beta[c] - mean * sc;   // shift
    }
}

__global__ void k_bnapply(float* __restrict__ out, const float* __restrict__ stats, int total4) {
    int i = blockIdx.x * TPB + threadIdx.x;
    if (i < total4) {
        float4 v = ((float4*)out)[i];
        int c0 = (i * 4) & (D_OUT - 1);
        v.x = v.x * stats[c0 + 0] + stats[32 + c0 + 0];
        v.y = v.y * stats[c0 + 1] + stats[32 + c0 + 1];
        v.z = v.z * stats[c0 + 2] + stats[32 + c0 + 2];
        v.w = v.w * stats[c0 + 3] + stats[32 + c0 + 3];
        ((float4*)out)[i] = v;
    }
}

// ---------------- launcher ----------------

extern "C" void kernel_launch(void* const* d_in, const int* in_sizes, int n_in,
                              void* d_out, int out_size, void* d_ws, size_t ws_size,
                              hipStream_t stream) {
    const float* x     = (const float*)d_in[0];
    const int* eidx    = (const int*)d_in[1];
    const float* attr  = (const float*)d_in[2];
    const float* W     = (const float*)d_in[3];
    const float* Wr    = (const float*)d_in[4];
    const float* bias  = (const float*)d_in[5];
    const float* gamma = (const float*)d_in[6];
    const float* beta  = (const float*)d_in[7];
    float* out = (float*)d_out;

    const int N = in_sizes[0] / D_IN;
    const int E = in_sizes[1] / 2;
    const int* src = eidx;
    const int* dst = eidx + E;

    const int nb = (N + TPB - 1) / TPB;          // <=512 required by k_scan_b
    const int gE = (E + TPB - 1) / TPB;
    const int nbAgg = (16 * N + TPB - 1) / TPB;  // 16 lanes per node
    const int nbRed = (nbAgg + 63) / 64;

    // workspace layout (4-byte elements)
    uint2* rec       = (uint2*)d_ws;                 // E (8B each)
    int* cnt         = (int*)(rec + E);              // N
    int* cursor      = cnt + N;                      // N
    int* bsum        = cursor + N;                   // nb
    int* boff        = bsum + nb;                    // nb
    float* partials  = (float*)(boff + nb);          // nbAgg * 64
    float* partials2 = partials + (size_t)nbAgg * 64;// nbRed * 64
    float* stats     = partials2 + (size_t)nbRed * 64; // 64: scale[32] shift[32]

    k_zero<<<nb, TPB, 0, stream>>>(cnt, N);
    k_hist<<<gE, TPB, 0, stream>>>(dst, cnt, E);
    k_scan_a<<<nb, TPB, 0, stream>>>(cnt, bsum, N);
    k_scan_b<<<1, 512, 0, stream>>>(bsum, boff, nb);
    k_scan_c<<<nb, TPB, 0, stream>>>(cnt, boff, cursor, N);
    k_scatter<<<gE, TPB, 0, stream>>>(src, dst, attr, cursor, rec, E);
    k_agg<<<nbAgg, TPB, 0, stream>>>(x, W, Wr, bias, cursor, rec, out, partials, N);
    k_red1<<<nbRed, TPB, 0, stream>>>(partials, partials2, nbAgg);
    k_bnfin<<<1, 128, 0, stream>>>(partials2, gamma, beta, stats, nbRed, N);
    int total4 = N * D_OUT / 4;
    k_bnapply<<<(total4 + TPB - 1) / TPB, TPB, 0, stream>>>(out, stats, total4);
}

// Round 4
// 371.064 us; speedup vs baseline: 4.2917x; 1.2803x over previous
//
#include <hip/hip_runtime.h>
#include <math.h>

#define TPB 256
#define D_IN 16
#define D_OUT 32
#define NUM_K 8
#define WPAD 516     // kernel-h stride in LDS for sW
#define SBN_LOG 9    // 512 nodes per superbucket
#define SBN 512
#define CT 4096      // coarse tile (edges per block)
#define EPT 16       // edges per thread in coarse pass

// ---------------- counting-sort pipeline ----------------

__global__ void k_zero(int* __restrict__ cnt, int N) {
    int i = blockIdx.x * TPB + threadIdx.x;
    if (i < N) cnt[i] = 0;
}

__global__ void k_hist(const int* __restrict__ dst, int* __restrict__ cnt, int E) {
    int e = blockIdx.x * TPB + threadIdx.x;
    if (e < E) atomicAdd(&cnt[dst[e]], 1);
}

__global__ void k_scan_a(const int* __restrict__ cnt, int* __restrict__ bsum, int N) {
    __shared__ int sd[TPB];
    int i = blockIdx.x * TPB + threadIdx.x;
    sd[threadIdx.x] = (i < N) ? cnt[i] : 0;
    __syncthreads();
    for (int s = TPB / 2; s > 0; s >>= 1) {
        if (threadIdx.x < s) sd[threadIdx.x] += sd[threadIdx.x + s];
        __syncthreads();
    }
    if (threadIdx.x == 0) bsum[blockIdx.x] = sd[0];
}

// single block, 512 threads: exclusive scan of block sums (nb <= 512)
__global__ void k_scan_b(const int* __restrict__ bsum, int* __restrict__ boff, int nb) {
    __shared__ int sd[512];
    int t = threadIdx.x;
    int own = (t < nb) ? bsum[t] : 0;
    sd[t] = own;
    __syncthreads();
    for (int s = 1; s < 512; s <<= 1) {
        int a = sd[t];
        int b = (t >= s) ? sd[t - s] : 0;
        __syncthreads();
        sd[t] = a + b;
        __syncthreads();
    }
    if (t < nb) boff[t] = sd[t] - own;   // exclusive
}

// cursor[i] = exclusive prefix (row start); also samples superbucket bases.
// After the scatter phase, cursor[i] == row end.
__global__ void k_scan_c(const int* __restrict__ cnt, const int* __restrict__ boff,
                         int* __restrict__ cursor, int* __restrict__ sbo,
                         int* __restrict__ scursor, int N, int E, int nsb) {
    __shared__ int sd[TPB];
    int t = threadIdx.x;
    int i = blockIdx.x * TPB + t;
    int v = (i < N) ? cnt[i] : 0;
    sd[t] = v;
    __syncthreads();
    for (int s = 1; s < TPB; s <<= 1) {
        int a = sd[t];
        int b = (t >= s) ? sd[t - s] : 0;
        __syncthreads();
        sd[t] = a + b;
        __syncthreads();
    }
    int excl = sd[t] - v + boff[blockIdx.x];
    if (i < N) {
        cursor[i] = excl;
        if ((i & (SBN - 1)) == 0) {
            sbo[i >> SBN_LOG] = excl;
            scursor[i >> SBN_LOG] = excl;
        }
    }
    if (i == 0) sbo[nsb] = E;
}

// -------- fallback single-pass scatter (used only if ws too small) --------
__global__ void k_scatter(const int* __restrict__ src, const int* __restrict__ dst,
                          const float* __restrict__ attr, int* __restrict__ cursor,
                          uint2* __restrict__ rec, int E) {
    int e = blockIdx.x * TPB + threadIdx.x;
    if (e < E) {
        float f0 = attr[3 * e + 0], f1 = attr[3 * e + 1], f2 = attr[3 * e + 2];
        int q0 = min((int)(f0 * 1024.f), 1023);
        int q1 = min((int)(f1 * 1024.f), 1023);
        int q2 = min((int)(f2 * 1024.f), 1023);
        unsigned pk = (unsigned)q0 | ((unsigned)q1 << 10) | ((unsigned)q2 << 20);
        int pos = atomicAdd(&cursor[dst[e]], 1);
        rec[pos] = make_uint2((unsigned)src[e], pk);
    }
}

// -------- coarse pass: LDS radix-partition edges into superbuckets --------
// tmp record: x = src(17b) | dst_local(9b)<<17 ; y = packed attr (30b)
__global__ __launch_bounds__(TPB) void k_coarse(
        const int* __restrict__ src, const int* __restrict__ dst,
        const float* __restrict__ attr, int* __restrict__ scursor,
        uint2* __restrict__ tmp, int E, int nsb) {
    __shared__ int hist[256];
    __shared__ int base[256];
    __shared__ int goff[256];
    __shared__ __align__(16) uint2 stage[CT];     // 32 KB
    __shared__ unsigned char ssb[CT];             // 4 KB

    int tile0 = blockIdx.x * CT;
    for (int i = threadIdx.x; i < 256; i += TPB) hist[i] = 0;
    __syncthreads();

    unsigned rx[EPT], ry[EPT];
    int rk[EPT], sbv[EPT];
#pragma unroll
    for (int i = 0; i < EPT; i++) {
        int e = tile0 + i * TPB + threadIdx.x;
        sbv[i] = -1;
        if (e < E) {
            int s = src[e], d = dst[e];
            float f0 = attr[3 * e + 0], f1 = attr[3 * e + 1], f2 = attr[3 * e + 2];
            int q0 = min((int)(f0 * 1024.f), 1023);
            int q1 = min((int)(f1 * 1024.f), 1023);
            int q2 = min((int)(f2 * 1024.f), 1023);
            int sb = d >> SBN_LOG;
            rx[i] = (unsigned)s | ((unsigned)(d & (SBN - 1)) << 17);
            ry[i] = (unsigned)q0 | ((unsigned)q1 << 10) | ((unsigned)q2 << 20);
            rk[i] = atomicAdd(&hist[sb], 1);
            sbv[i] = sb;
        }
    }
    __syncthreads();

    // Hillis-Steele inclusive scan over 256 buckets -> exclusive in 'excl'
    int t = threadIdx.x;
    int cntv = hist[t];
    base[t] = cntv;
    __syncthreads();
    for (int s = 1; s < 256; s <<= 1) {
        int add = (t >= s) ? base[t - s] : 0;
        __syncthreads();
        base[t] += add;
        __syncthreads();
    }
    int excl = base[t] - cntv;
    // reserve global space per non-empty bucket
    if (t < nsb && cntv > 0) goff[t] = atomicAdd(&scursor[t], cntv);
    __syncthreads();
    base[t] = excl;
    __syncthreads();

    // stage records grouped by bucket
#pragma unroll
    for (int i = 0; i < EPT; i++) {
        if (sbv[i] >= 0) {
            int slot = base[sbv[i]] + rk[i];
            stage[slot] = make_uint2(rx[i], ry[i]);
            ssb[slot] = (unsigned char)sbv[i];
        }
    }
    __syncthreads();

    // flush: consecutive slots of a bucket -> consecutive global positions
    int tileCount = min(E - tile0, CT);
    for (int j = threadIdx.x; j < tileCount; j += TPB) {
        int sb = ssb[j];
        tmp[goff[sb] + (j - base[sb])] = stage[j];
    }
}

// -------- fine pass: per-superbucket scatter to exact per-node positions --------
// Writes land in a ~131KB contiguous window (L2-resident) per superbucket.
__global__ void k_fine(const uint2* __restrict__ tmp, const int* __restrict__ sbo,
                       int* __restrict__ cursor, uint2* __restrict__ rec) {
    int b  = blockIdx.x >> 1;
    int sl = blockIdx.x & 1;
    int lo = sbo[b], hi = sbo[b + 1];
    for (int p = lo + sl * TPB + threadIdx.x; p < hi; p += 2 * TPB) {
        uint2 r = tmp[p];
        int dl = (int)((r.x >> 17) & (SBN - 1));
        int d  = (b << SBN_LOG) + dl;
        int pos = atomicAdd(&cursor[d], 1);
        rec[pos] = make_uint2(r.x & 0x1FFFFu, r.y);
    }
}

// ---------------- main aggregation: 16 lanes per node ----------------
// sub = lane-in-node (0..15), grp = sub>>3 (edge parity), h = sub&7 (spline kernel).

__global__ __launch_bounds__(TPB, 4) void k_agg(
    const float* __restrict__ x, const float* __restrict__ W,
    const float* __restrict__ Wr, const float* __restrict__ bias,
    const int* __restrict__ cursor, const uint2* __restrict__ rec,
    float* __restrict__ out, float* __restrict__ partials, int N) {

    __shared__ __align__(16) float sW[NUM_K * WPAD];   // ~16.5 KB
    __shared__ __align__(16) float sWr[D_IN * D_OUT];  // 2 KB
    __shared__ float sB[D_OUT];
    __shared__ float4 sStats[4][16];

    for (int idx = threadIdx.x; idx < NUM_K * D_IN * D_OUT; idx += TPB) {
        int k = idx >> 9, rem = idx & 511, i = rem >> 5, c = rem & 31;
        sW[k * WPAD + i * 32 + c] = W[idx];
    }
    for (int idx = threadIdx.x; idx < D_IN * D_OUT; idx += TPB) sWr[idx] = Wr[idx];
    if (threadIdx.x < D_OUT) sB[threadIdx.x] = bias[threadIdx.x];
    __syncthreads();

    int t   = blockIdx.x * TPB + threadIdx.x;
    int n   = t >> 4;
    int sub = t & 15;
    int grp = sub >> 3;
    int h   = sub & 7;
    bool valid = n < N;

    float4 g0 = {0,0,0,0}, g1 = {0,0,0,0}, g2 = {0,0,0,0}, g3 = {0,0,0,0};
    int deg = 0;
    if (valid) {
        int p0 = (n == 0) ? 0 : cursor[n - 1];   // cursor[n] == row end after scatter
        int p1 = cursor[n];
        deg = p1 - p0;
        int p = p0 + grp;
        if (p < p1) {
            int last = p1 - 1;
            uint2 r  = rec[p];
            uint2 rn = rec[min(p + 2, last)];
            const float4* xr = (const float4*)x + (size_t)r.x * 4;
            float4 xq0 = xr[0], xq1 = xr[1], xq2 = xr[2], xq3 = xr[3];
            for (; p < p1; p += 2) {
                uint2 rnn = rec[min(p + 4, last)];
                const float4* xnr = (const float4*)x + (size_t)rn.x * 4;
                float4 xn0 = xnr[0], xn1 = xnr[1], xn2 = xnr[2], xn3 = xnr[3];
                float f0 = ((float)(r.y & 1023u) + 0.5f) * (1.f / 1024.f);
                float f1 = ((float)((r.y >> 10) & 1023u) + 0.5f) * (1.f / 1024.f);
                float f2 = ((float)((r.y >> 20) & 1023u) + 0.5f) * (1.f / 1024.f);
                float b0 = (h & 1) ? f0 : 1.f - f0;
                float b1 = (h & 2) ? f1 : 1.f - f1;
                float b2 = (h & 4) ? f2 : 1.f - f2;
                float bs = b0 * b1 * b2;
                g0.x = fmaf(bs, xq0.x, g0.x); g0.y = fmaf(bs, xq0.y, g0.y);
                g0.z = fmaf(bs, xq0.z, g0.z); g0.w = fmaf(bs, xq0.w, g0.w);
                g1.x = fmaf(bs, xq1.x, g1.x); g1.y = fmaf(bs, xq1.y, g1.y);
                g1.z = fmaf(bs, xq1.z, g1.z); g1.w = fmaf(bs, xq1.w, g1.w);
                g2.x = fmaf(bs, xq2.x, g2.x); g2.y = fmaf(bs, xq2.y, g2.y);
                g2.z = fmaf(bs, xq2.z, g2.z); g2.w = fmaf(bs, xq2.w, g2.w);
                g3.x = fmaf(bs, xq3.x, g3.x); g3.y = fmaf(bs, xq3.y, g3.y);
                g3.z = fmaf(bs, xq3.z, g3.z); g3.w = fmaf(bs, xq3.w, g3.w);
                r = rn; rn = rnn;
                xq0 = xn0; xq1 = xn1; xq2 = xn2; xq3 = xn3;
            }
        }
    }

    // combine the two edge-groups (lanes sub and sub^8 share kernel h)
    g0.x += __shfl_xor(g0.x, 8); g0.y += __shfl_xor(g0.y, 8);
    g0.z += __shfl_xor(g0.z, 8); g0.w += __shfl_xor(g0.w, 8);
    g1.x += __shfl_xor(g1.x, 8); g1.y += __shfl_xor(g1.y, 8);
    g1.z += __shfl_xor(g1.z, 8); g1.w += __shfl_xor(g1.w, 8);
    g2.x += __shfl_xor(g2.x, 8); g2.y += __shfl_xor(g2.y, 8);
    g2.z += __shfl_xor(g2.z, 8); g2.w += __shfl_xor(g2.w, 8);
    g3.x += __shfl_xor(g3.x, 8); g3.y += __shfl_xor(g3.y, 8);
    g3.z += __shfl_xor(g3.z, 8); g3.w += __shfl_xor(g3.w, 8);

    // contraction: this lane computes channels [16*grp, 16*grp+16) for kernel h
    float4 o0 = {0,0,0,0}, o1 = {0,0,0,0}, o2 = {0,0,0,0}, o3 = {0,0,0,0};
    const float* wbase = sW + h * WPAD + grp * 16;
#define CONTRACT1(gv, i) { \
        const float4* wr_ = (const float4*)(wbase + (i) * 32); \
        float4 w0 = wr_[0], w1 = wr_[1], w2 = wr_[2], w3 = wr_[3]; \
        o0.x = fmaf(gv, w0.x, o0.x); o0.y = fmaf(gv, w0.y, o0.y); \
        o0.z = fmaf(gv, w0.z, o0.z); o0.w = fmaf(gv, w0.w, o0.w); \
        o1.x = fmaf(gv, w1.x, o1.x); o1.y = fmaf(gv, w1.y, o1.y); \
        o1.z = fmaf(gv, w1.z, o1.z); o1.w = fmaf(gv, w1.w, o1.w); \
        o2.x = fmaf(gv, w2.x, o2.x); o2.y = fmaf(gv, w2.y, o2.y); \
        o2.z = fmaf(gv, w2.z, o2.z); o2.w = fmaf(gv, w2.w, o2.w); \
        o3.x = fmaf(gv, w3.x, o3.x); o3.y = fmaf(gv, w3.y, o3.y); \
        o3.z = fmaf(gv, w3.z, o3.z); o3.w = fmaf(gv, w3.w, o3.w); }
    CONTRACT1(g0.x,  0) CONTRACT1(g0.y,  1) CONTRACT1(g0.z,  2) CONTRACT1(g0.w,  3)
    CONTRACT1(g1.x,  4) CONTRACT1(g1.y,  5) CONTRACT1(g1.z,  6) CONTRACT1(g1.w,  7)
    CONTRACT1(g2.x,  8) CONTRACT1(g2.y,  9) CONTRACT1(g2.z, 10) CONTRACT1(g2.w, 11)
    CONTRACT1(g3.x, 12) CONTRACT1(g3.y, 13) CONTRACT1(g3.z, 14) CONTRACT1(g3.w, 15)
#undef CONTRACT1

    float inv = 1.f / (float)(deg > 0 ? deg : 1);
    o0.x *= inv; o0.y *= inv; o0.z *= inv; o0.w *= inv;
    o1.x *= inv; o1.y *= inv; o1.z *= inv; o1.w *= inv;
    o2.x *= inv; o2.y *= inv; o2.z *= inv; o2.w *= inv;
    o3.x *= inv; o3.y *= inv; o3.z *= inv; o3.w *= inv;

    // reduce-scatter across the 8 h-lanes: 16 -> 8 -> 4 -> 2 channels
    bool hi4 = (h & 4) != 0;
    float4 k0, k1, s0, s1;
    k0 = hi4 ? o2 : o0; k1 = hi4 ? o3 : o1;
    s0 = hi4 ? o0 : o2; s1 = hi4 ? o1 : o3;
    k0.x += __shfl_xor(s0.x, 4); k0.y += __shfl_xor(s0.y, 4);
    k0.z += __shfl_xor(s0.z, 4); k0.w += __shfl_xor(s0.w, 4);
    k1.x += __shfl_xor(s1.x, 4); k1.y += __shfl_xor(s1.y, 4);
    k1.z += __shfl_xor(s1.z, 4); k1.w += __shfl_xor(s1.w, 4);

    bool hi2 = (h & 2) != 0;
    float4 m0 = hi2 ? k1 : k0;
    float4 sm = hi2 ? k0 : k1;
    m0.x += __shfl_xor(sm.x, 2); m0.y += __shfl_xor(sm.y, 2);
    m0.z += __shfl_xor(sm.z, 2); m0.w += __shfl_xor(sm.w, 2);

    bool hi1 = (h & 1) != 0;
    float e0 = hi1 ? m0.z : m0.x;
    float e1 = hi1 ? m0.w : m0.y;
    float sa = hi1 ? m0.x : m0.z;
    float sb_ = hi1 ? m0.y : m0.w;
    e0 += __shfl_xor(sa, 1);
    e1 += __shfl_xor(sb_, 1);
    // lane now owns channels c0 = 2*sub, c0+1

    int c0 = 2 * sub;
    if (valid) {
        const float4* xr = (const float4*)x + (size_t)n * 4;
        float4 r0 = xr[0], r1 = xr[1], r2 = xr[2], r3 = xr[3];
#define ROOT1(xv, i) { \
            float2 w = *(const float2*)(sWr + (i) * 32 + c0); \
            e0 = fmaf(xv, w.x, e0); e1 = fmaf(xv, w.y, e1); }
        ROOT1(r0.x,  0) ROOT1(r0.y,  1) ROOT1(r0.z,  2) ROOT1(r0.w,  3)
        ROOT1(r1.x,  4) ROOT1(r1.y,  5) ROOT1(r1.z,  6) ROOT1(r1.w,  7)
        ROOT1(r2.x,  8) ROOT1(r2.y,  9) ROOT1(r2.z, 10) ROOT1(r2.w, 11)
        ROOT1(r3.x, 12) ROOT1(r3.y, 13) ROOT1(r3.z, 14) ROOT1(r3.w, 15)
#undef ROOT1
    }

    float2 bb = *(const float2*)(sB + c0);
    e0 += bb.x; e1 += bb.y;
    e0 = e0 > 0.f ? e0 : (expf(e0) - 1.f);
    e1 = e1 > 0.f ? e1 : (expf(e1) - 1.f);

    if (valid) *(float2*)(out + (size_t)n * D_OUT + c0) = make_float2(e0, e1);

    // block-level batch stats (NO global atomics)
    float ss0 = valid ? e0 : 0.f, ss1 = valid ? e1 : 0.f;
    float q0 = ss0 * ss0, q1 = ss1 * ss1;
    ss0 += __shfl_xor(ss0, 16); ss1 += __shfl_xor(ss1, 16);
    q0  += __shfl_xor(q0, 16);  q1  += __shfl_xor(q1, 16);
    ss0 += __shfl_xor(ss0, 32); ss1 += __shfl_xor(ss1, 32);
    q0  += __shfl_xor(q0, 32);  q1  += __shfl_xor(q1, 32);
    if ((threadIdx.x & 63) < 16)
        sStats[threadIdx.x >> 6][sub] = make_float4(ss0, ss1, q0, q1);
    __syncthreads();
    if (threadIdx.x < 64) {
        const float* sf = (const float*)sStats;
        float v = sf[threadIdx.x] + sf[64 + threadIdx.x] +
                  sf[128 + threadIdx.x] + sf[192 + threadIdx.x];
        int ssub = threadIdx.x >> 2, comp = threadIdx.x & 3;
        int col = 2 * ssub + (comp & 1) + 32 * (comp >> 1);  // 0..31 sum, 32..63 sumsq
        partials[(size_t)blockIdx.x * 64 + col] = v;
    }
}

// ---------------- stats reduction + batchnorm ----------------

__global__ void k_red1(const float* __restrict__ partials, float* __restrict__ partials2,
                       int nrows) {
    __shared__ float sd[4][64];
    int col = threadIdx.x & 63, j = threadIdx.x >> 6;
    float v = 0.f;
    for (int k = 0; k < 16; k++) {
        int r = blockIdx.x * 64 + j * 16 + k;
        if (r < nrows) v += partials[(size_t)r * 64 + col];
    }
    sd[j][col] = v;
    __syncthreads();
    if (threadIdx.x < 64)
        partials2[(size_t)blockIdx.x * 64 + threadIdx.x] =
            sd[0][threadIdx.x] + sd[1][threadIdx.x] + sd[2][threadIdx.x] + sd[3][threadIdx.x];
}

__global__ void k_bnfin(const float* __restrict__ partials2, const float* __restrict__ gamma,
                        const float* __restrict__ beta, float* __restrict__ stats,
                        int nrows2, int N) {
    __shared__ float sd[2][64];
    int col = threadIdx.x & 63, j = threadIdx.x >> 6;   // 128 threads
    float v = 0.f;
    for (int r = j; r < nrows2; r += 2) v += partials2[(size_t)r * 64 + col];
    sd[j][col] = v;
    __syncthreads();
    if (threadIdx.x < 32) {
        int c = threadIdx.x;
        float S = sd[0][c] + sd[1][c];
        float Q = sd[0][32 + c] + sd[1][32 + c];
        float mean = S / (float)N;
        float var  = Q / (float)N - mean * mean;
        float sc   = gamma[c] * rsqrtf(var + 1e-5f);
        stats[c]      = sc;                    // scale
        stats[32 + c] = beta[c] - mean * sc;   // shift
    }
}

__global__ void k_bnapply(float* __restrict__ out, const float* __restrict__ stats, int total4) {
    int i = blockIdx.x * TPB + threadIdx.x;
    if (i < total4) {
        float4 v = ((float4*)out)[i];
        int c0 = (i * 4) & (D_OUT - 1);
        v.x = v.x * stats[c0 + 0] + stats[32 + c0 + 0];
        v.y = v.y * stats[c0 + 1] + stats[32 + c0 + 1];
        v.z = v.z * stats[c0 + 2] + stats[32 + c0 + 2];
        v.w = v.w * stats[c0 + 3] + stats[32 + c0 + 3];
        ((float4*)out)[i] = v;
    }
}

// ---------------- launcher ----------------

extern "C" void kernel_launch(void* const* d_in, const int* in_sizes, int n_in,
                              void* d_out, int out_size, void* d_ws, size_t ws_size,
                              hipStream_t stream) {
    const float* x     = (const float*)d_in[0];
    const int* eidx    = (const int*)d_in[1];
    const float* attr  = (const float*)d_in[2];
    const float* W     = (const float*)d_in[3];
    const float* Wr    = (const float*)d_in[4];
    const float* bias  = (const float*)d_in[5];
    const float* gamma = (const float*)d_in[6];
    const float* beta  = (const float*)d_in[7];
    float* out = (float*)d_out;

    const int N = in_sizes[0] / D_IN;
    const int E = in_sizes[1] / 2;
    const int* src = eidx;
    const int* dst = eidx + E;

    const int nb  = (N + TPB - 1) / TPB;          // <=512 required by k_scan_b
    const int gE  = (E + TPB - 1) / TPB;
    const int nsb = (N + SBN - 1) / SBN;          // superbuckets
    const int nbAgg = (16 * N + TPB - 1) / TPB;   // 16 lanes per node
    const int nbRed = (nbAgg + 63) / 64;
    const int gC  = (E + CT - 1) / CT;

    // workspace layout (4-byte elements)
    uint2* rec       = (uint2*)d_ws;                   // E (8B each)
    int* cnt         = (int*)(rec + E);                // N
    int* cursor      = cnt + N;                        // N
    int* bsum        = cursor + N;                     // nb
    int* boff        = bsum + nb;                      // nb
    int* sbo         = boff + nb;                      // nsb+1
    int* scursor     = sbo + nsb + 1;                  // nsb
    float* partials  = (float*)(scursor + nsb);        // nbAgg * 64
    float* partials2 = partials + (size_t)nbAgg * 64;  // nbRed * 64
    float* stats     = partials2 + (size_t)nbRed * 64; // 64
    uintptr_t tmp_addr = ((uintptr_t)(stats + 64) + 15) & ~(uintptr_t)15;
    uint2* tmp       = (uint2*)tmp_addr;               // E (two-pass path only)
    size_t need_twopass = (tmp_addr + (size_t)E * 8) - (uintptr_t)d_ws;
    bool twopass = (ws_size >= need_twopass) && (nsb <= 256) && (N <= 131072);

    k_zero<<<nb, TPB, 0, stream>>>(cnt, N);
    k_hist<<<gE, TPB, 0, stream>>>(dst, cnt, E);
    k_scan_a<<<nb, TPB, 0, stream>>>(cnt, bsum, N);
    k_scan_b<<<1, 512, 0, stream>>>(bsum, boff, nb);
    k_scan_c<<<nb, TPB, 0, stream>>>(cnt, boff, cursor, sbo, scursor, N, E, nsb);
    if (twopass) {
        k_coarse<<<gC, TPB, 0, stream>>>(src, dst, attr, scursor, tmp, E, nsb);
        k_fine<<<2 * nsb, TPB, 0, stream>>>(tmp, sbo, cursor, rec);
    } else {
        k_scatter<<<gE, TPB, 0, stream>>>(src, dst, attr, cursor, rec, E);
    }
    k_agg<<<nbAgg, TPB, 0, stream>>>(x, W, Wr, bias, cursor, rec, out, partials, N);
    k_red1<<<nbRed, TPB, 0, stream>>>(partials, partials2, nbAgg);
    k_bnfin<<<1, 128, 0, stream>>>(partials2, gamma, beta, stats, nbRed, N);
    int total4 = N * D_OUT / 4;
    k_bnapply<<<(total4 + TPB - 1) / TPB, TPB, 0, stream>>>(out, stats, total4);
}

// Round 5
// 211.952 us; speedup vs baseline: 7.5135x; 1.7507x over previous
//
#include <hip/hip_runtime.h>
#include <math.h>

#define TPB 256
#define FTPB 512     // fine-pass threads (one per superbucket node)
#define D_IN 16
#define D_OUT 32
#define NUM_K 8
#define WPAD 516     // kernel-h stride in LDS for sW
#define SBN_LOG 9    // 512 nodes per superbucket
#define SBN 512
#define CT 4096      // coarse tile (edges per block)
#define EPT 16       // edges per thread in coarse pass

// ---------------- superbucket counting (primary path) ----------------

__global__ void k_zero256(int* __restrict__ sbcnt) {
    sbcnt[threadIdx.x] = 0;
}

// grid-strided LDS histogram over <=256 superbuckets
__global__ void k_sbhist(const int* __restrict__ dst, int* __restrict__ sbcnt, int E) {
    __shared__ int h[256];
    for (int i = threadIdx.x; i < 256; i += TPB) h[i] = 0;
    __syncthreads();
    int stride = gridDim.x * TPB;
    for (int e = blockIdx.x * TPB + threadIdx.x; e < E; e += stride)
        atomicAdd(&h[dst[e] >> SBN_LOG], 1);
    __syncthreads();
    for (int i = threadIdx.x; i < 256; i += TPB)
        if (h[i]) atomicAdd(&sbcnt[i], h[i]);
}

// single block, 256 threads: exclusive scan of superbucket counts
__global__ void k_sbscan(const int* __restrict__ sbcnt, int* __restrict__ sbo,
                         int* __restrict__ scursor, int nsb, int E) {
    __shared__ int sd[256];
    int t = threadIdx.x;
    int own = (t < nsb) ? sbcnt[t] : 0;
    sd[t] = own;
    __syncthreads();
    for (int s = 1; s < 256; s <<= 1) {
        int add = (t >= s) ? sd[t - s] : 0;
        __syncthreads();
        sd[t] += add;
        __syncthreads();
    }
    if (t < nsb) { sbo[t] = sd[t] - own; scursor[t] = sd[t] - own; }
    if (t == 0) sbo[nsb] = E;
}

// -------- coarse pass: LDS radix-partition edges into superbuckets --------
// tmp record: x = src(17b) | dst_local(9b)<<17 ; y = packed attr (30b)
__global__ __launch_bounds__(TPB) void k_coarse(
        const int* __restrict__ src, const int* __restrict__ dst,
        const float* __restrict__ attr, int* __restrict__ scursor,
        uint2* __restrict__ tmp, int E, int nsb) {
    __shared__ int hist[256];
    __shared__ int base[256];
    __shared__ int goff[256];
    __shared__ __align__(16) uint2 stage[CT];     // 32 KB
    __shared__ unsigned char ssb[CT];             // 4 KB

    int tile0 = blockIdx.x * CT;
    for (int i = threadIdx.x; i < 256; i += TPB) hist[i] = 0;
    __syncthreads();

    unsigned rx[EPT], ry[EPT];
    int rk[EPT], sbv[EPT];
#pragma unroll
    for (int i = 0; i < EPT; i++) {
        int e = tile0 + i * TPB + threadIdx.x;
        sbv[i] = -1;
        if (e < E) {
            int s = src[e], d = dst[e];
            float f0 = attr[3 * e + 0], f1 = attr[3 * e + 1], f2 = attr[3 * e + 2];
            int q0 = min((int)(f0 * 1024.f), 1023);
            int q1 = min((int)(f1 * 1024.f), 1023);
            int q2 = min((int)(f2 * 1024.f), 1023);
            int sb = d >> SBN_LOG;
            rx[i] = (unsigned)s | ((unsigned)(d & (SBN - 1)) << 17);
            ry[i] = (unsigned)q0 | ((unsigned)q1 << 10) | ((unsigned)q2 << 20);
            rk[i] = atomicAdd(&hist[sb], 1);
            sbv[i] = sb;
        }
    }
    __syncthreads();

    // Hillis-Steele inclusive scan over 256 buckets -> exclusive in 'excl'
    int t = threadIdx.x;
    int cntv = hist[t];
    base[t] = cntv;
    __syncthreads();
    for (int s = 1; s < 256; s <<= 1) {
        int add = (t >= s) ? base[t - s] : 0;
        __syncthreads();
        base[t] += add;
        __syncthreads();
    }
    int excl = base[t] - cntv;
    // reserve global space per non-empty bucket
    if (t < nsb && cntv > 0) goff[t] = atomicAdd(&scursor[t], cntv);
    __syncthreads();
    base[t] = excl;
    __syncthreads();

    // stage records grouped by bucket
#pragma unroll
    for (int i = 0; i < EPT; i++) {
        if (sbv[i] >= 0) {
            int slot = base[sbv[i]] + rk[i];
            stage[slot] = make_uint2(rx[i], ry[i]);
            ssb[slot] = (unsigned char)sbv[i];
        }
    }
    __syncthreads();

    // flush: consecutive slots of a bucket -> consecutive global positions
    int tileCount = min(E - tile0, CT);
    for (int j = threadIdx.x; j < tileCount; j += TPB) {
        int sb = ssb[j];
        tmp[goff[sb] + (j - base[sb])] = stage[j];
    }
}

// -------- fine pass: per-superbucket LDS count + scan + scatter --------
// One 512-thread block per superbucket. Writes cursor[] row-ends and the
// final sorted rec[] -- no global atomics; all writes in an L2-resident window.
__global__ __launch_bounds__(FTPB) void k_fine2(
        const uint2* __restrict__ tmp, const int* __restrict__ sbo,
        int* __restrict__ cursor, uint2* __restrict__ rec, int N) {
    __shared__ int hist[SBN];
    __shared__ int scan[SBN];
    int b = blockIdx.x;
    int lo = sbo[b], hi = sbo[b + 1];
    int t = threadIdx.x;
    hist[t] = 0;
    __syncthreads();
    for (int p = lo + t; p < hi; p += FTPB)
        atomicAdd(&hist[(tmp[p].x >> 17) & (SBN - 1)], 1);
    __syncthreads();
    int own = hist[t];
    scan[t] = own;
    __syncthreads();
    for (int s = 1; s < SBN; s <<= 1) {
        int add = (t >= s) ? scan[t - s] : 0;
        __syncthreads();
        scan[t] += add;
        __syncthreads();
    }
    int incl = scan[t];
    int n = (b << SBN_LOG) + t;
    if (n < N) cursor[n] = lo + incl;     // row END (k_agg reads [cursor[n-1], cursor[n]))
    __syncthreads();
    hist[t] = lo + incl - own;            // exclusive start -> running LDS cursor
    __syncthreads();
    for (int p = lo + t; p < hi; p += FTPB) {
        uint2 r = tmp[p];
        int dl = (int)((r.x >> 17) & (SBN - 1));
        int slot = atomicAdd(&hist[dl], 1);
        rec[slot] = make_uint2(r.x & 0x1FFFFu, r.y);
    }
}

// ---------------- fallback single-pass pipeline (ws too small / N too big) ----------------

__global__ void k_zero(int* __restrict__ cnt, int N) {
    int i = blockIdx.x * TPB + threadIdx.x;
    if (i < N) cnt[i] = 0;
}

__global__ void k_hist(const int* __restrict__ dst, int* __restrict__ cnt, int E) {
    int e = blockIdx.x * TPB + threadIdx.x;
    if (e < E) atomicAdd(&cnt[dst[e]], 1);
}

__global__ void k_scan_a(const int* __restrict__ cnt, int* __restrict__ bsum, int N) {
    __shared__ int sd[TPB];
    int i = blockIdx.x * TPB + threadIdx.x;
    sd[threadIdx.x] = (i < N) ? cnt[i] : 0;
    __syncthreads();
    for (int s = TPB / 2; s > 0; s >>= 1) {
        if (threadIdx.x < s) sd[threadIdx.x] += sd[threadIdx.x + s];
        __syncthreads();
    }
    if (threadIdx.x == 0) bsum[blockIdx.x] = sd[0];
}

__global__ void k_scan_b(const int* __restrict__ bsum, int* __restrict__ boff, int nb) {
    __shared__ int sd[512];
    int t = threadIdx.x;
    int own = (t < nb) ? bsum[t] : 0;
    sd[t] = own;
    __syncthreads();
    for (int s = 1; s < 512; s <<= 1) {
        int a = sd[t];
        int b = (t >= s) ? sd[t - s] : 0;
        __syncthreads();
        sd[t] = a + b;
        __syncthreads();
    }
    if (t < nb) boff[t] = sd[t] - own;   // exclusive
}

__global__ void k_scan_c(const int* __restrict__ cnt, const int* __restrict__ boff,
                         int* __restrict__ cursor, int N) {
    __shared__ int sd[TPB];
    int t = threadIdx.x;
    int i = blockIdx.x * TPB + t;
    int v = (i < N) ? cnt[i] : 0;
    sd[t] = v;
    __syncthreads();
    for (int s = 1; s < TPB; s <<= 1) {
        int a = sd[t];
        int b = (t >= s) ? sd[t - s] : 0;
        __syncthreads();
        sd[t] = a + b;
        __syncthreads();
    }
    if (i < N) cursor[i] = sd[t] - v + boff[blockIdx.x];
}

__global__ void k_scatter(const int* __restrict__ src, const int* __restrict__ dst,
                          const float* __restrict__ attr, int* __restrict__ cursor,
                          uint2* __restrict__ rec, int E) {
    int e = blockIdx.x * TPB + threadIdx.x;
    if (e < E) {
        float f0 = attr[3 * e + 0], f1 = attr[3 * e + 1], f2 = attr[3 * e + 2];
        int q0 = min((int)(f0 * 1024.f), 1023);
        int q1 = min((int)(f1 * 1024.f), 1023);
        int q2 = min((int)(f2 * 1024.f), 1023);
        unsigned pk = (unsigned)q0 | ((unsigned)q1 << 10) | ((unsigned)q2 << 20);
        int pos = atomicAdd(&cursor[dst[e]], 1);
        rec[pos] = make_uint2((unsigned)src[e], pk);
    }
}

// ---------------- main aggregation: 16 lanes per node ----------------
// sub = lane-in-node (0..15), grp = sub>>3 (edge parity), h = sub&7 (spline kernel).

__global__ __launch_bounds__(TPB, 4) void k_agg(
    const float* __restrict__ x, const float* __restrict__ W,
    const float* __restrict__ Wr, const float* __restrict__ bias,
    const int* __restrict__ cursor, const uint2* __restrict__ rec,
    float* __restrict__ out, float* __restrict__ partials, int N) {

    __shared__ __align__(16) float sW[NUM_K * WPAD];   // ~16.5 KB
    __shared__ __align__(16) float sWr[D_IN * D_OUT];  // 2 KB
    __shared__ float sB[D_OUT];
    __shared__ float4 sStats[4][16];

    for (int idx = threadIdx.x; idx < NUM_K * D_IN * D_OUT; idx += TPB) {
        int k = idx >> 9, rem = idx & 511, i = rem >> 5, c = rem & 31;
        sW[k * WPAD + i * 32 + c] = W[idx];
    }
    for (int idx = threadIdx.x; idx < D_IN * D_OUT; idx += TPB) sWr[idx] = Wr[idx];
    if (threadIdx.x < D_OUT) sB[threadIdx.x] = bias[threadIdx.x];
    __syncthreads();

    int t   = blockIdx.x * TPB + threadIdx.x;
    int n   = t >> 4;
    int sub = t & 15;
    int grp = sub >> 3;
    int h   = sub & 7;
    bool valid = n < N;

    float4 g0 = {0,0,0,0}, g1 = {0,0,0,0}, g2 = {0,0,0,0}, g3 = {0,0,0,0};
    int deg = 0;
    if (valid) {
        int p0 = (n == 0) ? 0 : cursor[n - 1];   // cursor[n] == row end
        int p1 = cursor[n];
        deg = p1 - p0;
        int p = p0 + grp;
        if (p < p1) {
            int last = p1 - 1;
            uint2 r  = rec[p];
            uint2 rn = rec[min(p + 2, last)];
            const float4* xr = (const float4*)x + (size_t)r.x * 4;
            float4 xq0 = xr[0], xq1 = xr[1], xq2 = xr[2], xq3 = xr[3];
            for (; p < p1; p += 2) {
                uint2 rnn = rec[min(p + 4, last)];
                const float4* xnr = (const float4*)x + (size_t)rn.x * 4;
                float4 xn0 = xnr[0], xn1 = xnr[1], xn2 = xnr[2], xn3 = xnr[3];
                float f0 = ((float)(r.y & 1023u) + 0.5f) * (1.f / 1024.f);
                float f1 = ((float)((r.y >> 10) & 1023u) + 0.5f) * (1.f / 1024.f);
                float f2 = ((float)((r.y >> 20) & 1023u) + 0.5f) * (1.f / 1024.f);
                float b0 = (h & 1) ? f0 : 1.f - f0;
                float b1 = (h & 2) ? f1 : 1.f - f1;
                float b2 = (h & 4) ? f2 : 1.f - f2;
                float bs = b0 * b1 * b2;
                g0.x = fmaf(bs, xq0.x, g0.x); g0.y = fmaf(bs, xq0.y, g0.y);
                g0.z = fmaf(bs, xq0.z, g0.z); g0.w = fmaf(bs, xq0.w, g0.w);
                g1.x = fmaf(bs, xq1.x, g1.x); g1.y = fmaf(bs, xq1.y, g1.y);
                g1.z = fmaf(bs, xq1.z, g1.z); g1.w = fmaf(bs, xq1.w, g1.w);
                g2.x = fmaf(bs, xq2.x, g2.x); g2.y = fmaf(bs, xq2.y, g2.y);
                g2.z = fmaf(bs, xq2.z, g2.z); g2.w = fmaf(bs, xq2.w, g2.w);
                g3.x = fmaf(bs, xq3.x, g3.x); g3.y = fmaf(bs, xq3.y, g3.y);
                g3.z = fmaf(bs, xq3.z, g3.z); g3.w = fmaf(bs, xq3.w, g3.w);
                r = rn; rn = rnn;
                xq0 = xn0; xq1 = xn1; xq2 = xn2; xq3 = xn3;
            }
        }
    }

    // combine the two edge-groups (lanes sub and sub^8 share kernel h)
    g0.x += __shfl_xor(g0.x, 8); g0.y += __shfl_xor(g0.y, 8);
    g0.z += __shfl_xor(g0.z, 8); g0.w += __shfl_xor(g0.w, 8);
    g1.x += __shfl_xor(g1.x, 8); g1.y += __shfl_xor(g1.y, 8);
    g1.z += __shfl_xor(g1.z, 8); g1.w += __shfl_xor(g1.w, 8);
    g2.x += __shfl_xor(g2.x, 8); g2.y += __shfl_xor(g2.y, 8);
    g2.z += __shfl_xor(g2.z, 8); g2.w += __shfl_xor(g2.w, 8);
    g3.x += __shfl_xor(g3.x, 8); g3.y += __shfl_xor(g3.y, 8);
    g3.z += __shfl_xor(g3.z, 8); g3.w += __shfl_xor(g3.w, 8);

    // contraction: this lane computes channels [16*grp, 16*grp+16) for kernel h
    float4 o0 = {0,0,0,0}, o1 = {0,0,0,0}, o2 = {0,0,0,0}, o3 = {0,0,0,0};
    const float* wbase = sW + h * WPAD + grp * 16;
#define CONTRACT1(gv, i) { \
        const float4* wr_ = (const float4*)(wbase + (i) * 32); \
        float4 w0 = wr_[0], w1 = wr_[1], w2 = wr_[2], w3 = wr_[3]; \
        o0.x = fmaf(gv, w0.x, o0.x); o0.y = fmaf(gv, w0.y, o0.y); \
        o0.z = fmaf(gv, w0.z, o0.z); o0.w = fmaf(gv, w0.w, o0.w); \
        o1.x = fmaf(gv, w1.x, o1.x); o1.y = fmaf(gv, w1.y, o1.y); \
        o1.z = fmaf(gv, w1.z, o1.z); o1.w = fmaf(gv, w1.w, o1.w); \
        o2.x = fmaf(gv, w2.x, o2.x); o2.y = fmaf(gv, w2.y, o2.y); \
        o2.z = fmaf(gv, w2.z, o2.z); o2.w = fmaf(gv, w2.w, o2.w); \
        o3.x = fmaf(gv, w3.x, o3.x); o3.y = fmaf(gv, w3.y, o3.y); \
        o3.z = fmaf(gv, w3.z, o3.z); o3.w = fmaf(gv, w3.w, o3.w); }
    CONTRACT1(g0.x,  0) CONTRACT1(g0.y,  1) CONTRACT1(g0.z,  2) CONTRACT1(g0.w,  3)
    CONTRACT1(g1.x,  4) CONTRACT1(g1.y,  5) CONTRACT1(g1.z,  6) CONTRACT1(g1.w,  7)
    CONTRACT1(g2.x,  8) CONTRACT1(g2.y,  9) CONTRACT1(g2.z, 10) CONTRACT1(g2.w, 11)
    CONTRACT1(g3.x, 12) CONTRACT1(g3.y, 13) CONTRACT1(g3.z, 14) CONTRACT1(g3.w, 15)
#undef CONTRACT1

    float inv = 1.f / (float)(deg > 0 ? deg : 1);
    o0.x *= inv; o0.y *= inv; o0.z *= inv; o0.w *= inv;
    o1.x *= inv; o1.y *= inv; o1.z *= inv; o1.w *= inv;
    o2.x *= inv; o2.y *= inv; o2.z *= inv; o2.w *= inv;
    o3.x *= inv; o3.y *= inv; o3.z *= inv; o3.w *= inv;

    // reduce-scatter across the 8 h-lanes: 16 -> 8 -> 4 -> 2 channels
    bool hi4 = (h & 4) != 0;
    float4 k0, k1, s0, s1;
    k0 = hi4 ? o2 : o0; k1 = hi4 ? o3 : o1;
    s0 = hi4 ? o0 : o2; s1 = hi4 ? o1 : o3;
    k0.x += __shfl_xor(s0.x, 4); k0.y += __shfl_xor(s0.y, 4);
    k0.z += __shfl_xor(s0.z, 4); k0.w += __shfl_xor(s0.w, 4);
    k1.x += __shfl_xor(s1.x, 4); k1.y += __shfl_xor(s1.y, 4);
    k1.z += __shfl_xor(s1.z, 4); k1.w += __shfl_xor(s1.w, 4);

    bool hi2 = (h & 2) != 0;
    float4 m0 = hi2 ? k1 : k0;
    float4 sm = hi2 ? k0 : k1;
    m0.x += __shfl_xor(sm.x, 2); m0.y += __shfl_xor(sm.y, 2);
    m0.z += __shfl_xor(sm.z, 2); m0.w += __shfl_xor(sm.w, 2);

    bool hi1 = (h & 1) != 0;
    float e0 = hi1 ? m0.z : m0.x;
    float e1 = hi1 ? m0.w : m0.y;
    float sa = hi1 ? m0.x : m0.z;
    float sb_ = hi1 ? m0.y : m0.w;
    e0 += __shfl_xor(sa, 1);
    e1 += __shfl_xor(sb_, 1);
    // lane now owns channels c0 = 2*sub, c0+1

    int c0 = 2 * sub;
    if (valid) {
        const float4* xr = (const float4*)x + (size_t)n * 4;
        float4 r0 = xr[0], r1 = xr[1], r2 = xr[2], r3 = xr[3];
#define ROOT1(xv, i) { \
            float2 w = *(const float2*)(sWr + (i) * 32 + c0); \
            e0 = fmaf(xv, w.x, e0); e1 = fmaf(xv, w.y, e1); }
        ROOT1(r0.x,  0) ROOT1(r0.y,  1) ROOT1(r0.z,  2) ROOT1(r0.w,  3)
        ROOT1(r1.x,  4) ROOT1(r1.y,  5) ROOT1(r1.z,  6) ROOT1(r1.w,  7)
        ROOT1(r2.x,  8) ROOT1(r2.y,  9) ROOT1(r2.z, 10) ROOT1(r2.w, 11)
        ROOT1(r3.x, 12) ROOT1(r3.y, 13) ROOT1(r3.z, 14) ROOT1(r3.w, 15)
#undef ROOT1
    }

    float2 bb = *(const float2*)(sB + c0);
    e0 += bb.x; e1 += bb.y;
    e0 = e0 > 0.f ? e0 : (expf(e0) - 1.f);
    e1 = e1 > 0.f ? e1 : (expf(e1) - 1.f);

    if (valid) *(float2*)(out + (size_t)n * D_OUT + c0) = make_float2(e0, e1);

    // block-level batch stats (NO global atomics)
    float ss0 = valid ? e0 : 0.f, ss1 = valid ? e1 : 0.f;
    float q0 = ss0 * ss0, q1 = ss1 * ss1;
    ss0 += __shfl_xor(ss0, 16); ss1 += __shfl_xor(ss1, 16);
    q0  += __shfl_xor(q0, 16);  q1  += __shfl_xor(q1, 16);
    ss0 += __shfl_xor(ss0, 32); ss1 += __shfl_xor(ss1, 32);
    q0  += __shfl_xor(q0, 32);  q1  += __shfl_xor(q1, 32);
    if ((threadIdx.x & 63) < 16)
        sStats[threadIdx.x >> 6][sub] = make_float4(ss0, ss1, q0, q1);
    __syncthreads();
    if (threadIdx.x < 64) {
        const float* sf = (const float*)sStats;
        float v = sf[threadIdx.x] + sf[64 + threadIdx.x] +
                  sf[128 + threadIdx.x] + sf[192 + threadIdx.x];
        int ssub = threadIdx.x >> 2, comp = threadIdx.x & 3;
        int col = 2 * ssub + (comp & 1) + 32 * (comp >> 1);  // 0..31 sum, 32..63 sumsq
        partials[(size_t)blockIdx.x * 64 + col] = v;
    }
}

// ---------------- stats reduction + batchnorm ----------------

__global__ void k_red1(const float* __restrict__ partials, float* __restrict__ partials2,
                       int nrows) {
    __shared__ float sd[4][64];
    int col = threadIdx.x & 63, j = threadIdx.x >> 6;
    float v = 0.f;
    for (int k = 0; k < 16; k++) {
        int r = blockIdx.x * 64 + j * 16 + k;
        if (r < nrows) v += partials[(size_t)r * 64 + col];
    }
    sd[j][col] = v;
    __syncthreads();
    if (threadIdx.x < 64)
        partials2[(size_t)blockIdx.x * 64 + threadIdx.x] =
            sd[0][threadIdx.x] + sd[1][threadIdx.x] + sd[2][threadIdx.x] + sd[3][threadIdx.x];
}

__global__ void k_bnfin(const float* __restrict__ partials2, const float* __restrict__ gamma,
                        const float* __restrict__ beta, float* __restrict__ stats,
                        int nrows2, int N) {
    __shared__ float sd[2][64];
    int col = threadIdx.x & 63, j = threadIdx.x >> 6;   // 128 threads
    float v = 0.f;
    for (int r = j; r < nrows2; r += 2) v += partials2[(size_t)r * 64 + col];
    sd[j][col] = v;
    __syncthreads();
    if (threadIdx.x < 32) {
        int c = threadIdx.x;
        float S = sd[0][c] + sd[1][c];
        float Q = sd[0][32 + c] + sd[1][32 + c];
        float mean = S / (float)N;
        float var  = Q / (float)N - mean * mean;
        float sc   = gamma[c] * rsqrtf(var + 1e-5f);
        stats[c]      = sc;                    // scale
        stats[32 + c] = beta[c] - mean * sc;   // shift
    }
}

__global__ void k_bnapply(float* __restrict__ out, const float* __restrict__ stats, int total4) {
    int i = blockIdx.x * TPB + threadIdx.x;
    if (i < total4) {
        float4 v = ((float4*)out)[i];
        int c0 = (i * 4) & (D_OUT - 1);
        v.x = v.x * stats[c0 + 0] + stats[32 + c0 + 0];
        v.y = v.y * stats[c0 + 1] + stats[32 + c0 + 1];
        v.z = v.z * stats[c0 + 2] + stats[32 + c0 + 2];
        v.w = v.w * stats[c0 + 3] + stats[32 + c0 + 3];
        ((float4*)out)[i] = v;
    }
}

// ---------------- launcher ----------------

extern "C" void kernel_launch(void* const* d_in, const int* in_sizes, int n_in,
                              void* d_out, int out_size, void* d_ws, size_t ws_size,
                              hipStream_t stream) {
    const float* x     = (const float*)d_in[0];
    const int* eidx    = (const int*)d_in[1];
    const float* attr  = (const float*)d_in[2];
    const float* W     = (const float*)d_in[3];
    const float* Wr    = (const float*)d_in[4];
    const float* bias  = (const float*)d_in[5];
    const float* gamma = (const float*)d_in[6];
    const float* beta  = (const float*)d_in[7];
    float* out = (float*)d_out;

    const int N = in_sizes[0] / D_IN;
    const int E = in_sizes[1] / 2;
    const int* src = eidx;
    const int* dst = eidx + E;

    const int nb  = (N + TPB - 1) / TPB;
    const int gE  = (E + TPB - 1) / TPB;
    const int nsb = (N + SBN - 1) / SBN;          // superbuckets
    const int nbAgg = (16 * N + TPB - 1) / TPB;   // 16 lanes per node
    const int nbRed = (nbAgg + 63) / 64;
    const int gC  = (E + CT - 1) / CT;

    // workspace layout (shared head)
    uint2* rec       = (uint2*)d_ws;                   // E (8B each)
    int* cursor      = (int*)(rec + E);                // N
    float* partials  = (float*)(cursor + N);           // nbAgg * 64
    float* partials2 = partials + (size_t)nbAgg * 64;  // nbRed * 64
    float* stats     = partials2 + (size_t)nbRed * 64; // 64
    int* sbcnt       = (int*)(stats + 64);             // 256
    int* sbo         = sbcnt + 256;                    // nsb+1 (<=257)
    int* scursor     = sbo + 257;                      // nsb (<=256)
    uintptr_t tail   = ((uintptr_t)(scursor + 256) + 15) & ~(uintptr_t)15;
    // primary path: tmp[E]; fallback path reuses tail for cnt/bsum/boff
    uint2* tmp       = (uint2*)tail;                   // E
    size_t need_primary  = (tail + (size_t)E * 8) - (uintptr_t)d_ws;
    size_t need_fallback = (tail + ((size_t)N + 2 * nb) * 4) - (uintptr_t)d_ws;
    bool primary = (ws_size >= need_primary) && (nsb <= 256) && (nb <= 512);

    if (primary) {
        k_zero256<<<1, 256, 0, stream>>>(sbcnt);
        int gH = min(1024, gE);
        k_sbhist<<<gH, TPB, 0, stream>>>(dst, sbcnt, E);
        k_sbscan<<<1, 256, 0, stream>>>(sbcnt, sbo, scursor, nsb, E);
        k_coarse<<<gC, TPB, 0, stream>>>(src, dst, attr, scursor, tmp, E, nsb);
        k_fine2<<<nsb, FTPB, 0, stream>>>(tmp, sbo, cursor, rec, N);
    } else if (ws_size >= need_fallback && nb <= 512) {
        int* cnt  = (int*)tail;          // N
        int* bsum = cnt + N;             // nb
        int* boff = bsum + nb;           // nb
        k_zero<<<nb, TPB, 0, stream>>>(cnt, N);
        k_hist<<<gE, TPB, 0, stream>>>(dst, cnt, E);
        k_scan_a<<<nb, TPB, 0, stream>>>(cnt, bsum, N);
        k_scan_b<<<1, 512, 0, stream>>>(bsum, boff, nb);
        k_scan_c<<<nb, TPB, 0, stream>>>(cnt, boff, cursor, N);
        k_scatter<<<gE, TPB, 0, stream>>>(src, dst, attr, cursor, rec, E);
    }

    k_agg<<<nbAgg, TPB, 0, stream>>>(x, W, Wr, bias, cursor, rec, out, partials, N);
    k_red1<<<nbRed, TPB, 0, stream>>>(partials, partials2, nbAgg);
    k_bnfin<<<1, 128, 0, stream>>>(partials2, gamma, beta, stats, nbRed, N);
    int total4 = N * D_OUT / 4;
    k_bnapply<<<(total4 + TPB - 1) / TPB, TPB, 0, stream>>>(out, stats, total4);
}